// Round 1
// baseline (9201.881 us; speedup 1.0000x reference)
//
#include <hip/hip_runtime.h>

// GIN encoder: 3 × [scatter-agg, MLP(128->128->D), BatchNorm(train), ReLU] + mean-pool
// N=100000 nodes, E=1600000 edges, G=128 graphs, fp32 throughout (baseline round).

#define N_NODES 100000
#define N_EDGES 1600000
#define N_GRAPHS 128
#define BN_EPS 1e-5f

// ---------------------------------------------------------------- helpers
__device__ __forceinline__ float4 bn_relu4(float4 v, const float* __restrict__ scale,
                                           const float* __restrict__ shift, int c4) {
  // scale/shift==nullptr -> identity (layer 0 input is raw x)
  if (scale != nullptr) {
    float4 sc = ((const float4*)scale)[c4];
    float4 sh = ((const float4*)shift)[c4];
    v.x = fmaxf(fmaf(v.x, sc.x, sh.x), 0.0f);
    v.y = fmaxf(fmaf(v.y, sc.y, sh.y), 0.0f);
    v.z = fmaxf(fmaf(v.z, sc.z, sh.z), 0.0f);
    v.w = fmaxf(fmaf(v.w, sc.w, sh.w), 0.0f);
  }
  return v;
}

// ---------------------------------------------------------------- agg init: agg[i] = act(in[i])
// d = 128 fixed -> 32 float4 per row.
__global__ void act_copy_kernel(const float* __restrict__ in, const float* __restrict__ scale,
                                const float* __restrict__ shift, float* __restrict__ out,
                                int total4) {
  int i = blockIdx.x * blockDim.x + threadIdx.x;
  if (i >= total4) return;
  float4 v = ((const float4*)in)[i];
  v = bn_relu4(v, scale, shift, i & 31);
  ((float4*)out)[i] = v;
}

// ---------------------------------------------------------------- edge scatter: agg[dst] += act(in[src])
// 32 consecutive threads handle one edge (one float4 each) -> coalesced 512B gather,
// contiguous atomics on the destination row.
__global__ __launch_bounds__(256) void scatter_add_kernel(
    const float* __restrict__ in, const float* __restrict__ scale,
    const float* __restrict__ shift, const int* __restrict__ src,
    const int* __restrict__ dst, float* __restrict__ agg) {
  int gid = blockIdx.x * 256 + threadIdx.x;
  int e = gid >> 5;
  if (e >= N_EDGES) return;
  int c4 = gid & 31;
  int s = src[e];
  int t = dst[e];
  float4 v = ((const float4*)(in + (size_t)s * 128))[c4];
  v = bn_relu4(v, scale, shift, c4);
  float* base = agg + (size_t)t * 128 + c4 * 4;
  atomicAdd(base + 0, v.x);
  atomicAdd(base + 1, v.y);
  atomicAdd(base + 2, v.z);
  atomicAdd(base + 3, v.w);
}

// ---------------------------------------------------------------- MLP matmul: O = [relu](A @ W + b)
// A: M x 128, W: 128 x DOUT row-major. Weights fully staged in LDS.
// Block = 256 threads; each thread owns a 4x4 register tile (4 rows x 4 cols).
// STATS: accumulate column sum/sumsq of O into gstats[0..2*DOUT) via LDS + global atomics.
template <int DOUT, bool RELU, bool STATS>
__global__ __launch_bounds__(256) void mlp_kernel(
    const float* __restrict__ A, const float* __restrict__ W,
    const float* __restrict__ bias, float* __restrict__ O,
    float* __restrict__ gstats, int M) {
  constexpr int C4 = DOUT / 4;    // float4 col groups (32 or 16)
  constexpr int RG = 256 / C4;    // row groups per block (8 or 16)
  constexpr int ROWS = RG * 4;    // rows per block (32 or 64)

  __shared__ float sW[128 * DOUT];
  __shared__ float sX[ROWS * 128];
  float4* sW4 = (float4*)sW;
  float4* sX4 = (float4*)sX;

  for (int i = threadIdx.x; i < 128 * DOUT / 4; i += 256)
    sW4[i] = ((const float4*)W)[i];

  int row0 = blockIdx.x * ROWS;
  const float4* A4 = (const float4*)(A + (size_t)row0 * 128);
  for (int i = threadIdx.x; i < ROWS * 32; i += 256) {
    int r = i >> 5;
    float4 z = make_float4(0.f, 0.f, 0.f, 0.f);
    sX4[i] = (row0 + r < M) ? A4[i] : z;
  }
  __syncthreads();

  int cg = threadIdx.x % C4;   // column group -> cols [4cg, 4cg+3]
  int rg = threadIdx.x / C4;   // row group    -> rows [4rg, 4rg+3] (local)

  float4 acc[4];
  float4 bv = ((const float4*)bias)[cg];
#pragma unroll
  for (int r = 0; r < 4; ++r) acc[r] = bv;

  for (int k4 = 0; k4 < 32; ++k4) {
    float4 xv[4];
#pragma unroll
    for (int r = 0; r < 4; ++r) xv[r] = sX4[(rg * 4 + r) * 32 + k4];
#pragma unroll
    for (int kk = 0; kk < 4; ++kk) {
      float4 wv = sW4[(k4 * 4 + kk) * C4 + cg];
#pragma unroll
      for (int r = 0; r < 4; ++r) {
        float x = (&xv[r].x)[kk];
        acc[r].x = fmaf(x, wv.x, acc[r].x);
        acc[r].y = fmaf(x, wv.y, acc[r].y);
        acc[r].z = fmaf(x, wv.z, acc[r].z);
        acc[r].w = fmaf(x, wv.w, acc[r].w);
      }
    }
  }

  // store (with optional relu)
#pragma unroll
  for (int r = 0; r < 4; ++r) {
    int row = row0 + rg * 4 + r;
    if (row < M) {
      float4 v = acc[r];
      if (RELU) {
        v.x = fmaxf(v.x, 0.f); v.y = fmaxf(v.y, 0.f);
        v.z = fmaxf(v.z, 0.f); v.w = fmaxf(v.w, 0.f);
      }
      ((float4*)(O + (size_t)row * DOUT))[cg] = v;
    }
  }

  if (STATS) {
    // per-thread partials over its (valid) 4 rows
    float s[4] = {0.f, 0.f, 0.f, 0.f}, ss[4] = {0.f, 0.f, 0.f, 0.f};
#pragma unroll
    for (int r = 0; r < 4; ++r) {
      if (row0 + rg * 4 + r < M) {
#pragma unroll
        for (int j = 0; j < 4; ++j) {
          float v = (&acc[r].x)[j];
          s[j] += v;
          ss[j] += v * v;
        }
      }
    }
    __syncthreads();           // sX no longer needed
    float* sSt = sX;           // reuse: [0..DOUT) sums, [DOUT..2*DOUT) sumsq
    for (int i = threadIdx.x; i < 2 * DOUT; i += 256) sSt[i] = 0.f;
    __syncthreads();
#pragma unroll
    for (int j = 0; j < 4; ++j) {
      atomicAdd(&sSt[cg * 4 + j], s[j]);
      atomicAdd(&sSt[DOUT + cg * 4 + j], ss[j]);
    }
    __syncthreads();
    for (int i = threadIdx.x; i < 2 * DOUT; i += 256) atomicAdd(&gstats[i], sSt[i]);
  }
}

// ---------------------------------------------------------------- BN finalize: stats -> scale/shift
template <int DOUT>
__global__ void finalize_stats_kernel(float* __restrict__ stats, const float* __restrict__ g,
                                      const float* __restrict__ be) {
  int c = threadIdx.x;
  if (c < DOUT) {
    float inv_n = 1.0f / (float)N_NODES;
    float mean = stats[c] * inv_n;
    float var = stats[DOUT + c] * inv_n - mean * mean;
    float sc = g[c] * rsqrtf(var + BN_EPS);
    stats[2 * DOUT + c] = sc;
    stats[3 * DOUT + c] = be[c] - mean * sc;
  }
}

// ---------------------------------------------------------------- mean pool (applies final BN+ReLU)
__global__ __launch_bounds__(256) void pool_kernel(
    const float* __restrict__ h, const float* __restrict__ scale,
    const float* __restrict__ shift, const int* __restrict__ batch,
    float* __restrict__ sums, float* __restrict__ cnts) {
  int gid = blockIdx.x * 256 + threadIdx.x;
  int node = gid >> 4;   // 16 threads per node (64 cols / 4)
  if (node >= N_NODES) return;
  int c4 = gid & 15;
  int g = batch[node];
  float4 v = ((const float4*)(h + (size_t)node * 64))[c4];
  float4 sc = ((const float4*)scale)[c4];
  float4 sh = ((const float4*)shift)[c4];
  v.x = fmaxf(fmaf(v.x, sc.x, sh.x), 0.f);
  v.y = fmaxf(fmaf(v.y, sc.y, sh.y), 0.f);
  v.z = fmaxf(fmaf(v.z, sc.z, sh.z), 0.f);
  v.w = fmaxf(fmaf(v.w, sc.w, sh.w), 0.f);
  float* base = sums + g * 64 + c4 * 4;
  atomicAdd(base + 0, v.x);
  atomicAdd(base + 1, v.y);
  atomicAdd(base + 2, v.z);
  atomicAdd(base + 3, v.w);
  if (c4 == 0) atomicAdd(&cnts[g], 1.0f);
}

__global__ void div_kernel(const float* __restrict__ sums, const float* __restrict__ cnts,
                           float* __restrict__ out) {
  int i = blockIdx.x * blockDim.x + threadIdx.x;
  if (i < N_GRAPHS * 64) out[i] = sums[i] / fmaxf(cnts[i >> 6], 1.0f);
}

// ---------------------------------------------------------------- launch
extern "C" void kernel_launch(void* const* d_in, const int* in_sizes, int n_in,
                              void* d_out, int out_size, void* d_ws, size_t ws_size,
                              hipStream_t stream) {
  const float* x = (const float*)d_in[0];
  const int* edge_index = (const int*)d_in[1];
  const int* batch = (const int*)d_in[2];
  const int* src = edge_index;            // edge_index[0]
  const int* dst = edge_index + N_EDGES;  // edge_index[1]

  const float* wa[3] = {(const float*)d_in[3], (const float*)d_in[9],  (const float*)d_in[15]};
  const float* ba[3] = {(const float*)d_in[4], (const float*)d_in[10], (const float*)d_in[16]};
  const float* wb[3] = {(const float*)d_in[5], (const float*)d_in[11], (const float*)d_in[17]};
  const float* bb[3] = {(const float*)d_in[6], (const float*)d_in[12], (const float*)d_in[18]};
  const float* gg[3] = {(const float*)d_in[7], (const float*)d_in[13], (const float*)d_in[19]};
  const float* be[3] = {(const float*)d_in[8], (const float*)d_in[14], (const float*)d_in[20]};

  // workspace layout (floats)
  float* buf0 = (float*)d_ws;                       // N*128
  float* buf1 = buf0 + (size_t)N_NODES * 128;       // N*128
  float* stats0 = buf1 + (size_t)N_NODES * 128;     // 4*128: sum, sumsq, scale, shift
  float* stats1 = stats0 + 512;                     // 4*128
  float* stats2 = stats1 + 512;                     // 4*64
  float* psums = stats2 + 256;                      // G*64
  float* pcnts = psums + (size_t)N_GRAPHS * 64;     // G
  size_t needed = ((size_t)N_NODES * 256 + 512 + 512 + 256 + N_GRAPHS * 64 + N_GRAPHS) * 4;
  if (ws_size < needed) return;

  // zero stats + pool accumulators (contiguous region) in one memset
  size_t zbytes = (512 + 512 + 256 + (size_t)N_GRAPHS * 64 + N_GRAPHS) * 4;
  hipMemsetAsync(stats0, 0, zbytes, stream);

  const int total4 = N_NODES * 32;
  const int copy_blocks = (total4 + 255) / 256;
  const int scat_blocks = (N_EDGES * 32) / 256;

  // ---- layer 0: in = x (no BN), agg->buf0, mid->buf1, out->buf0, stats0
  act_copy_kernel<<<copy_blocks, 256, 0, stream>>>(x, nullptr, nullptr, buf0, total4);
  scatter_add_kernel<<<scat_blocks, 256, 0, stream>>>(x, nullptr, nullptr, src, dst, buf0);
  mlp_kernel<128, true, false><<<3125, 256, 0, stream>>>(buf0, wa[0], ba[0], buf1, nullptr, N_NODES);
  mlp_kernel<128, false, true><<<3125, 256, 0, stream>>>(buf1, wb[0], bb[0], buf0, stats0, N_NODES);
  finalize_stats_kernel<128><<<1, 128, 0, stream>>>(stats0, gg[0], be[0]);

  // ---- layer 1: in = buf0 (BN0 applied on the fly), agg->buf1, mid->buf0, out->buf1, stats1
  act_copy_kernel<<<copy_blocks, 256, 0, stream>>>(buf0, stats0 + 256, stats0 + 384, buf1, total4);
  scatter_add_kernel<<<scat_blocks, 256, 0, stream>>>(buf0, stats0 + 256, stats0 + 384, src, dst, buf1);
  mlp_kernel<128, true, false><<<3125, 256, 0, stream>>>(buf1, wa[1], ba[1], buf0, nullptr, N_NODES);
  mlp_kernel<128, false, true><<<3125, 256, 0, stream>>>(buf0, wb[1], bb[1], buf1, stats1, N_NODES);
  finalize_stats_kernel<128><<<1, 128, 0, stream>>>(stats1, gg[1], be[1]);

  // ---- layer 2: in = buf1 (BN1), agg->buf0, mid->buf1, out(N x 64)->buf0, stats2
  act_copy_kernel<<<copy_blocks, 256, 0, stream>>>(buf1, stats1 + 256, stats1 + 384, buf0, total4);
  scatter_add_kernel<<<scat_blocks, 256, 0, stream>>>(buf1, stats1 + 256, stats1 + 384, src, dst, buf0);
  mlp_kernel<128, true, false><<<3125, 256, 0, stream>>>(buf0, wa[2], ba[2], buf1, nullptr, N_NODES);
  mlp_kernel<64, false, true><<<1563, 256, 0, stream>>>(buf1, wb[2], bb[2], buf0, stats2, N_NODES);
  finalize_stats_kernel<64><<<1, 64, 0, stream>>>(stats2, gg[2], be[2]);

  // ---- pool: BN2+ReLU on the fly, segment mean over sorted batch
  pool_kernel<<<(N_NODES * 16 + 255) / 256, 256, 0, stream>>>(
      buf0, stats2 + 128, stats2 + 192, batch, psums, pcnts);
  div_kernel<<<32, 256, 0, stream>>>(psums, pcnts, (float*)d_out);
}

// Round 2
// 1879.905 us; speedup vs baseline: 4.8949x; 4.8949x over previous
//
#include <hip/hip_runtime.h>

// GIN encoder: 3 x [CSR gather-agg, MLP(128->128->D), BatchNorm(train), ReLU] + mean-pool
// N=100000 nodes, E=1600000 edges, G=128 graphs, fp32.
// R2: CSR-based aggregation (no destination atomics), BN+ReLU applied in place.

#define N_NODES 100000
#define N_EDGES 1600000
#define N_GRAPHS 128
#define BN_EPS 1e-5f

// ---------------------------------------------------------------- helpers
__device__ __forceinline__ float4 bn_relu4(float4 v, const float* __restrict__ scale,
                                           const float* __restrict__ shift, int c4) {
  float4 sc = ((const float4*)scale)[c4];
  float4 sh = ((const float4*)shift)[c4];
  v.x = fmaxf(fmaf(v.x, sc.x, sh.x), 0.0f);
  v.y = fmaxf(fmaf(v.y, sc.y, sh.y), 0.0f);
  v.z = fmaxf(fmaf(v.z, sc.z, sh.z), 0.0f);
  v.w = fmaxf(fmaf(v.w, sc.w, sh.w), 0.0f);
  return v;
}

// ---------------------------------------------------------------- CSR build
__global__ __launch_bounds__(256) void hist_kernel(const int* __restrict__ dst,
                                                   int* __restrict__ deg) {
  int e = blockIdx.x * 256 + threadIdx.x;
  if (e < N_EDGES) atomicAdd(&deg[dst[e]], 1);
}

// one-block exclusive scan: row_ptr[0]=0, row_ptr[i+1]=sum(deg[0..i])
__global__ __launch_bounds__(256) void scan_kernel(const int* __restrict__ deg,
                                                   int* __restrict__ row_ptr) {
  __shared__ int tmp[256];
  __shared__ int carry;
  int tid = threadIdx.x;
  if (tid == 0) { carry = 0; row_ptr[0] = 0; }
  __syncthreads();
  for (int base = 0; base < N_NODES; base += 1024) {
    int i0 = base + tid * 4;
    int a[4], s[4];
#pragma unroll
    for (int j = 0; j < 4; ++j) a[j] = (i0 + j < N_NODES) ? deg[i0 + j] : 0;
    s[0] = a[0]; s[1] = s[0] + a[1]; s[2] = s[1] + a[2]; s[3] = s[2] + a[3];
    tmp[tid] = s[3];
    __syncthreads();
    for (int off = 1; off < 256; off <<= 1) {
      int t = (tid >= off) ? tmp[tid - off] : 0;
      __syncthreads();
      tmp[tid] += t;
      __syncthreads();
    }
    int prev = (tid > 0) ? tmp[tid - 1] : 0;
    int c = carry;
#pragma unroll
    for (int j = 0; j < 4; ++j)
      if (i0 + j < N_NODES) row_ptr[i0 + j + 1] = c + prev + s[j];
    __syncthreads();
    if (tid == 255) carry = c + tmp[255];
    __syncthreads();
  }
}

__global__ __launch_bounds__(256) void cursor_init_kernel(const int* __restrict__ row_ptr,
                                                          int* __restrict__ cursor) {
  int i = blockIdx.x * 256 + threadIdx.x;
  if (i < N_NODES) cursor[i] = row_ptr[i];
}

__global__ __launch_bounds__(256) void fill_kernel(const int* __restrict__ src,
                                                   const int* __restrict__ dst,
                                                   int* __restrict__ cursor,
                                                   int* __restrict__ adj) {
  int e = blockIdx.x * 256 + threadIdx.x;
  if (e < N_EDGES) {
    int pos = atomicAdd(&cursor[dst[e]], 1);
    adj[pos] = src[e];
  }
}

// ---------------------------------------------------------------- gather agg: agg[n] = in[n] + sum_{s in adj[n]} in[s]
// 32 threads per node, one float4 column each -> 512B coalesced row reads.
__global__ __launch_bounds__(256) void gather_agg_kernel(
    const float* __restrict__ in, const int* __restrict__ row_ptr,
    const int* __restrict__ adj, float* __restrict__ agg) {
  int gid = blockIdx.x * 256 + threadIdx.x;
  int n = gid >> 5;
  if (n >= N_NODES) return;
  int c4 = gid & 31;
  int beg = row_ptr[n], end = row_ptr[n + 1];
  float4 v = ((const float4*)(in + (size_t)n * 128))[c4];
  for (int k = beg; k < end; ++k) {
    int s = adj[k];
    float4 u = ((const float4*)(in + (size_t)s * 128))[c4];
    v.x += u.x; v.y += u.y; v.z += u.z; v.w += u.w;
  }
  ((float4*)(agg + (size_t)n * 128))[c4] = v;
}

// ---------------------------------------------------------------- fallback atomic scatter (if ws too small for CSR)
__global__ __launch_bounds__(256) void copy_kernel(const float* __restrict__ in,
                                                   float* __restrict__ out, int total4) {
  int i = blockIdx.x * blockDim.x + threadIdx.x;
  if (i < total4) ((float4*)out)[i] = ((const float4*)in)[i];
}

__global__ __launch_bounds__(256) void scatter_add_kernel(
    const float* __restrict__ in, const int* __restrict__ src,
    const int* __restrict__ dst, float* __restrict__ agg) {
  int gid = blockIdx.x * 256 + threadIdx.x;
  int e = gid >> 5;
  if (e >= N_EDGES) return;
  int c4 = gid & 31;
  int s = src[e];
  int t = dst[e];
  float4 v = ((const float4*)(in + (size_t)s * 128))[c4];
  float* base = agg + (size_t)t * 128 + c4 * 4;
  atomicAdd(base + 0, v.x);
  atomicAdd(base + 1, v.y);
  atomicAdd(base + 2, v.z);
  atomicAdd(base + 3, v.w);
}

// ---------------------------------------------------------------- MLP matmul: O = [relu](A @ W + b)
// A: M x 128, W: 128 x DOUT row-major. Weights fully staged in LDS.
// Block = 256 threads; each thread owns a 4x4 register tile.
// STATS: accumulate column sum/sumsq of O into gstats[0..2*DOUT).
template <int DOUT, bool RELU, bool STATS>
__global__ __launch_bounds__(256) void mlp_kernel(
    const float* __restrict__ A, const float* __restrict__ W,
    const float* __restrict__ bias, float* __restrict__ O,
    float* __restrict__ gstats, int M) {
  constexpr int C4 = DOUT / 4;
  constexpr int RG = 256 / C4;
  constexpr int ROWS = RG * 4;

  __shared__ float sW[128 * DOUT];
  __shared__ float sX[ROWS * 128];
  float4* sW4 = (float4*)sW;
  float4* sX4 = (float4*)sX;

  for (int i = threadIdx.x; i < 128 * DOUT / 4; i += 256)
    sW4[i] = ((const float4*)W)[i];

  int row0 = blockIdx.x * ROWS;
  const float4* A4 = (const float4*)(A + (size_t)row0 * 128);
  for (int i = threadIdx.x; i < ROWS * 32; i += 256) {
    int r = i >> 5;
    float4 z = make_float4(0.f, 0.f, 0.f, 0.f);
    sX4[i] = (row0 + r < M) ? A4[i] : z;
  }
  __syncthreads();

  int cg = threadIdx.x % C4;
  int rg = threadIdx.x / C4;

  float4 acc[4];
  float4 bv = ((const float4*)bias)[cg];
#pragma unroll
  for (int r = 0; r < 4; ++r) acc[r] = bv;

  for (int k4 = 0; k4 < 32; ++k4) {
    float4 xv[4];
#pragma unroll
    for (int r = 0; r < 4; ++r) xv[r] = sX4[(rg * 4 + r) * 32 + k4];
#pragma unroll
    for (int kk = 0; kk < 4; ++kk) {
      float4 wv = sW4[(k4 * 4 + kk) * C4 + cg];
#pragma unroll
      for (int r = 0; r < 4; ++r) {
        float x = (&xv[r].x)[kk];
        acc[r].x = fmaf(x, wv.x, acc[r].x);
        acc[r].y = fmaf(x, wv.y, acc[r].y);
        acc[r].z = fmaf(x, wv.z, acc[r].z);
        acc[r].w = fmaf(x, wv.w, acc[r].w);
      }
    }
  }

#pragma unroll
  for (int r = 0; r < 4; ++r) {
    int row = row0 + rg * 4 + r;
    if (row < M) {
      float4 v = acc[r];
      if (RELU) {
        v.x = fmaxf(v.x, 0.f); v.y = fmaxf(v.y, 0.f);
        v.z = fmaxf(v.z, 0.f); v.w = fmaxf(v.w, 0.f);
      }
      ((float4*)(O + (size_t)row * DOUT))[cg] = v;
    }
  }

  if (STATS) {
    float s[4] = {0.f, 0.f, 0.f, 0.f}, ss[4] = {0.f, 0.f, 0.f, 0.f};
#pragma unroll
    for (int r = 0; r < 4; ++r) {
      if (row0 + rg * 4 + r < M) {
#pragma unroll
        for (int j = 0; j < 4; ++j) {
          float v = (&acc[r].x)[j];
          s[j] += v;
          ss[j] += v * v;
        }
      }
    }
    __syncthreads();
    float* sSt = sX;
    for (int i = threadIdx.x; i < 2 * DOUT; i += 256) sSt[i] = 0.f;
    __syncthreads();
#pragma unroll
    for (int j = 0; j < 4; ++j) {
      atomicAdd(&sSt[cg * 4 + j], s[j]);
      atomicAdd(&sSt[DOUT + cg * 4 + j], ss[j]);
    }
    __syncthreads();
    for (int i = threadIdx.x; i < 2 * DOUT; i += 256) atomicAdd(&gstats[i], sSt[i]);
  }
}

// ---------------------------------------------------------------- BN finalize: stats -> scale/shift
template <int DOUT>
__global__ void finalize_stats_kernel(float* __restrict__ stats, const float* __restrict__ g,
                                      const float* __restrict__ be) {
  int c = threadIdx.x;
  if (c < DOUT) {
    float inv_n = 1.0f / (float)N_NODES;
    float mean = stats[c] * inv_n;
    float var = stats[DOUT + c] * inv_n - mean * mean;
    float sc = g[c] * rsqrtf(var + BN_EPS);
    stats[2 * DOUT + c] = sc;
    stats[3 * DOUT + c] = be[c] - mean * sc;
  }
}

// ---------------------------------------------------------------- BN+ReLU in place
__global__ __launch_bounds__(256) void act_inplace_kernel(float* __restrict__ h,
                                                          const float* __restrict__ scale,
                                                          const float* __restrict__ shift,
                                                          int total4, int c4mask) {
  int i = blockIdx.x * blockDim.x + threadIdx.x;
  if (i >= total4) return;
  float4 v = ((float4*)h)[i];
  v = bn_relu4(v, scale, shift, i & c4mask);
  ((float4*)h)[i] = v;
}

// ---------------------------------------------------------------- mean pool (input already post-act)
__global__ __launch_bounds__(256) void pool_kernel(
    const float* __restrict__ h, const int* __restrict__ batch,
    float* __restrict__ sums, float* __restrict__ cnts) {
  int gid = blockIdx.x * 256 + threadIdx.x;
  int node = gid >> 4;
  if (node >= N_NODES) return;
  int c4 = gid & 15;
  int g = batch[node];
  float4 v = ((const float4*)(h + (size_t)node * 64))[c4];
  float* base = sums + g * 64 + c4 * 4;
  atomicAdd(base + 0, v.x);
  atomicAdd(base + 1, v.y);
  atomicAdd(base + 2, v.z);
  atomicAdd(base + 3, v.w);
  if (c4 == 0) atomicAdd(&cnts[g], 1.0f);
}

__global__ void div_kernel(const float* __restrict__ sums, const float* __restrict__ cnts,
                           float* __restrict__ out) {
  int i = blockIdx.x * blockDim.x + threadIdx.x;
  if (i < N_GRAPHS * 64) out[i] = sums[i] / fmaxf(cnts[i >> 6], 1.0f);
}

// ---------------------------------------------------------------- launch
extern "C" void kernel_launch(void* const* d_in, const int* in_sizes, int n_in,
                              void* d_out, int out_size, void* d_ws, size_t ws_size,
                              hipStream_t stream) {
  const float* x = (const float*)d_in[0];
  const int* edge_index = (const int*)d_in[1];
  const int* batch = (const int*)d_in[2];
  const int* src = edge_index;
  const int* dst = edge_index + N_EDGES;

  const float* wa[3] = {(const float*)d_in[3], (const float*)d_in[9],  (const float*)d_in[15]};
  const float* ba[3] = {(const float*)d_in[4], (const float*)d_in[10], (const float*)d_in[16]};
  const float* wb[3] = {(const float*)d_in[5], (const float*)d_in[11], (const float*)d_in[17]};
  const float* bb[3] = {(const float*)d_in[6], (const float*)d_in[12], (const float*)d_in[18]};
  const float* gg[3] = {(const float*)d_in[7], (const float*)d_in[13], (const float*)d_in[19]};
  const float* be[3] = {(const float*)d_in[8], (const float*)d_in[14], (const float*)d_in[20]};

  // workspace layout (floats first, then ints)
  float* buf0 = (float*)d_ws;                       // N*128
  float* buf1 = buf0 + (size_t)N_NODES * 128;       // N*128
  float* stats0 = buf1 + (size_t)N_NODES * 128;     // 512: sum, sumsq, scale, shift
  float* stats1 = stats0 + 512;                     // 512
  float* stats2 = stats1 + 512;                     // 256
  float* psums = stats2 + 256;                      // G*64
  float* pcnts = psums + (size_t)N_GRAPHS * 64;     // G
  size_t n_floats = (size_t)N_NODES * 256 + 512 + 512 + 256 + (size_t)N_GRAPHS * 64 + N_GRAPHS;
  int* row_ptr = (int*)(pcnts + N_GRAPHS);          // N+1
  int* deg = row_ptr + (N_NODES + 1);               // N (reused as cursor)
  int* adj = deg + N_NODES;                         // E
  size_t needed_base = n_floats * 4;
  size_t needed_csr = needed_base + ((size_t)(N_NODES + 1) + N_NODES + N_EDGES) * 4;
  if (ws_size < needed_base) return;
  bool use_csr = ws_size >= needed_csr;

  // zero stats + pool accumulators in one memset
  size_t zbytes = (512 + 512 + 256 + (size_t)N_GRAPHS * 64 + N_GRAPHS) * 4;
  hipMemsetAsync(stats0, 0, zbytes, stream);

  const int total4_128 = N_NODES * 32;
  const int copy_blocks = (total4_128 + 255) / 256;
  const int eb = (N_EDGES + 255) / 256;         // edge-parallel blocks
  const int nb = (N_NODES + 255) / 256;         // node-parallel blocks
  const int gather_blocks = (N_NODES * 32 + 255) / 256;
  const int scat_blocks = (N_EDGES * 32) / 256;

  if (use_csr) {
    hipMemsetAsync(deg, 0, N_NODES * 4, stream);
    hist_kernel<<<eb, 256, 0, stream>>>(dst, deg);
    scan_kernel<<<1, 256, 0, stream>>>(deg, row_ptr);
    cursor_init_kernel<<<nb, 256, 0, stream>>>(row_ptr, deg);  // deg becomes cursor
    fill_kernel<<<eb, 256, 0, stream>>>(src, dst, deg, adj);
  }

  // per layer: gather-agg -> mlp1(relu) -> mlp2(stats) -> finalize -> act in place
  const float* in = x;
  float* bufs[2] = {buf0, buf1};
  float* stats[3] = {stats0, stats1, stats2};
  const int douts[3] = {128, 128, 64};

  for (int l = 0; l < 3; ++l) {
    float* agg = bufs[l & 1];          // L0: buf0, L1: buf1, L2: buf0
    float* mid = bufs[(l + 1) & 1];
    float* out = agg == buf0 ? buf0 : buf1;  // mlp2 writes back over agg's buffer slot
    // actually: mlp1 agg->mid, mlp2 mid->agg's buffer (safe: agg consumed by mlp1)
    if (use_csr) {
      gather_agg_kernel<<<gather_blocks, 256, 0, stream>>>(in, row_ptr, adj, agg);
    } else {
      copy_kernel<<<copy_blocks, 256, 0, stream>>>(in, agg, total4_128);
      scatter_add_kernel<<<scat_blocks, 256, 0, stream>>>(in, src, dst, agg);
    }
    mlp_kernel<128, true, false><<<3125, 256, 0, stream>>>(agg, wa[l], ba[l], mid, nullptr, N_NODES);
    if (douts[l] == 128) {
      mlp_kernel<128, false, true><<<3125, 256, 0, stream>>>(mid, wb[l], bb[l], out, stats[l], N_NODES);
      finalize_stats_kernel<128><<<1, 128, 0, stream>>>(stats[l], gg[l], be[l]);
      act_inplace_kernel<<<copy_blocks, 256, 0, stream>>>(out, stats[l] + 256, stats[l] + 384,
                                                          total4_128, 31);
    } else {
      mlp_kernel<64, false, true><<<1563, 256, 0, stream>>>(mid, wb[l], bb[l], out, stats[l], N_NODES);
      finalize_stats_kernel<64><<<1, 64, 0, stream>>>(stats[l], gg[l], be[l]);
      act_inplace_kernel<<<(N_NODES * 16 + 255) / 256, 256, 0, stream>>>(
          out, stats[l] + 128, stats[l] + 192, N_NODES * 16, 15);
    }
    in = out;
  }

  // pool over post-act final features (N x 64 in buf0)
  pool_kernel<<<(N_NODES * 16 + 255) / 256, 256, 0, stream>>>(in, batch, psums, pcnts);
  div_kernel<<<32, 256, 0, stream>>>(psums, pcnts, (float*)d_out);
}

// Round 3
// 1365.099 us; speedup vs baseline: 6.7408x; 1.3771x over previous
//
#include <hip/hip_runtime.h>

// GIN encoder: 3 x [CSR gather-agg(+fused BN/ReLU), MLP(128->128->D), BN-stats] + segmented mean-pool
// N=100000 nodes, E=1600000 edges, G=128 graphs, fp32.
// R3: segmented pool (LDS-staged, ~30k global atomics instead of 6.4M),
//     counts via binary search, BN+ReLU fused into gather/pool reads.

#define N_NODES 100000
#define N_EDGES 1600000
#define N_GRAPHS 128
#define BN_EPS 1e-5f
#define POOL_CHUNK 400
#define POOL_BLOCKS ((N_NODES + POOL_CHUNK - 1) / POOL_CHUNK)  // 250

// ---------------------------------------------------------------- helpers
__device__ __forceinline__ float4 bn_relu4v(float4 v, float4 sc, float4 sh) {
  v.x = fmaxf(fmaf(v.x, sc.x, sh.x), 0.0f);
  v.y = fmaxf(fmaf(v.y, sc.y, sh.y), 0.0f);
  v.z = fmaxf(fmaf(v.z, sc.z, sh.z), 0.0f);
  v.w = fmaxf(fmaf(v.w, sc.w, sh.w), 0.0f);
  return v;
}

// ---------------------------------------------------------------- CSR build
__global__ __launch_bounds__(256) void hist_kernel(const int* __restrict__ dst,
                                                   int* __restrict__ deg) {
  int e = blockIdx.x * 256 + threadIdx.x;
  if (e < N_EDGES) atomicAdd(&deg[dst[e]], 1);
}

// one-block exclusive scan: row_ptr[0]=0, row_ptr[i+1]=sum(deg[0..i])
__global__ __launch_bounds__(256) void scan_kernel(const int* __restrict__ deg,
                                                   int* __restrict__ row_ptr) {
  __shared__ int tmp[256];
  __shared__ int carry;
  int tid = threadIdx.x;
  if (tid == 0) { carry = 0; row_ptr[0] = 0; }
  __syncthreads();
  for (int base = 0; base < N_NODES; base += 1024) {
    int i0 = base + tid * 4;
    int a[4], s[4];
#pragma unroll
    for (int j = 0; j < 4; ++j) a[j] = (i0 + j < N_NODES) ? deg[i0 + j] : 0;
    s[0] = a[0]; s[1] = s[0] + a[1]; s[2] = s[1] + a[2]; s[3] = s[2] + a[3];
    tmp[tid] = s[3];
    __syncthreads();
    for (int off = 1; off < 256; off <<= 1) {
      int t = (tid >= off) ? tmp[tid - off] : 0;
      __syncthreads();
      tmp[tid] += t;
      __syncthreads();
    }
    int prev = (tid > 0) ? tmp[tid - 1] : 0;
    int c = carry;
#pragma unroll
    for (int j = 0; j < 4; ++j)
      if (i0 + j < N_NODES) row_ptr[i0 + j + 1] = c + prev + s[j];
    __syncthreads();
    if (tid == 255) carry = c + tmp[255];
    __syncthreads();
  }
}

__global__ __launch_bounds__(256) void cursor_init_kernel(const int* __restrict__ row_ptr,
                                                          int* __restrict__ cursor) {
  int i = blockIdx.x * 256 + threadIdx.x;
  if (i < N_NODES) cursor[i] = row_ptr[i];
}

__global__ __launch_bounds__(256) void fill_kernel(const int* __restrict__ src,
                                                   const int* __restrict__ dst,
                                                   int* __restrict__ cursor,
                                                   int* __restrict__ adj) {
  int e = blockIdx.x * 256 + threadIdx.x;
  if (e < N_EDGES) {
    int pos = atomicAdd(&cursor[dst[e]], 1);
    adj[pos] = src[e];
  }
}

// ---------------------------------------------------------------- gather agg
// agg[n] = act(in[n]) + sum_{s in adj[n]} act(in[s]); act = BN+ReLU (or identity, layer 0)
// 32 threads per node, one float4 column each.
template <bool BN>
__global__ __launch_bounds__(256) void gather_agg_kernel(
    const float* __restrict__ in, const float* __restrict__ scale,
    const float* __restrict__ shift, const int* __restrict__ row_ptr,
    const int* __restrict__ adj, float* __restrict__ agg) {
  int gid = blockIdx.x * 256 + threadIdx.x;
  int n = gid >> 5;
  if (n >= N_NODES) return;
  int c4 = gid & 31;
  float4 sc, sh;
  if (BN) {
    sc = ((const float4*)scale)[c4];
    sh = ((const float4*)shift)[c4];
  }
  int beg = row_ptr[n], end = row_ptr[n + 1];
  float4 v = ((const float4*)(in + (size_t)n * 128))[c4];
  if (BN) v = bn_relu4v(v, sc, sh);
  for (int k = beg; k < end; ++k) {
    int s = adj[k];
    float4 u = ((const float4*)(in + (size_t)s * 128))[c4];
    if (BN) u = bn_relu4v(u, sc, sh);
    v.x += u.x; v.y += u.y; v.z += u.z; v.w += u.w;
  }
  ((float4*)(agg + (size_t)n * 128))[c4] = v;
}

// ---------------------------------------------------------------- fallback atomic scatter path
template <bool BN>
__global__ __launch_bounds__(256) void act_copy_kernel(const float* __restrict__ in,
                                                       const float* __restrict__ scale,
                                                       const float* __restrict__ shift,
                                                       float* __restrict__ out, int total4) {
  int i = blockIdx.x * blockDim.x + threadIdx.x;
  if (i >= total4) return;
  float4 v = ((const float4*)in)[i];
  if (BN) v = bn_relu4v(v, ((const float4*)scale)[i & 31], ((const float4*)shift)[i & 31]);
  ((float4*)out)[i] = v;
}

template <bool BN>
__global__ __launch_bounds__(256) void scatter_add_kernel(
    const float* __restrict__ in, const float* __restrict__ scale,
    const float* __restrict__ shift, const int* __restrict__ src,
    const int* __restrict__ dst, float* __restrict__ agg) {
  int gid = blockIdx.x * 256 + threadIdx.x;
  int e = gid >> 5;
  if (e >= N_EDGES) return;
  int c4 = gid & 31;
  int s = src[e];
  int t = dst[e];
  float4 v = ((const float4*)(in + (size_t)s * 128))[c4];
  if (BN) v = bn_relu4v(v, ((const float4*)scale)[c4], ((const float4*)shift)[c4]);
  float* base = agg + (size_t)t * 128 + c4 * 4;
  atomicAdd(base + 0, v.x);
  atomicAdd(base + 1, v.y);
  atomicAdd(base + 2, v.z);
  atomicAdd(base + 3, v.w);
}

// ---------------------------------------------------------------- MLP matmul: O = [relu](A @ W + b)
// A: M x 128, W: 128 x DOUT row-major. Weights fully staged in LDS.
// Block = 256 threads; each thread owns a 4x4 register tile.
// STATS: accumulate column sum/sumsq of O into gstats[0..2*DOUT).
template <int DOUT, bool RELU, bool STATS>
__global__ __launch_bounds__(256) void mlp_kernel(
    const float* __restrict__ A, const float* __restrict__ W,
    const float* __restrict__ bias, float* __restrict__ O,
    float* __restrict__ gstats, int M) {
  constexpr int C4 = DOUT / 4;
  constexpr int RG = 256 / C4;
  constexpr int ROWS = RG * 4;

  __shared__ float sW[128 * DOUT];
  __shared__ float sX[ROWS * 128];
  float4* sW4 = (float4*)sW;
  float4* sX4 = (float4*)sX;

  for (int i = threadIdx.x; i < 128 * DOUT / 4; i += 256)
    sW4[i] = ((const float4*)W)[i];

  int row0 = blockIdx.x * ROWS;
  const float4* A4 = (const float4*)(A + (size_t)row0 * 128);
  for (int i = threadIdx.x; i < ROWS * 32; i += 256) {
    int r = i >> 5;
    float4 z = make_float4(0.f, 0.f, 0.f, 0.f);
    sX4[i] = (row0 + r < M) ? A4[i] : z;
  }
  __syncthreads();

  int cg = threadIdx.x % C4;
  int rg = threadIdx.x / C4;

  float4 acc[4];
  float4 bv = ((const float4*)bias)[cg];
#pragma unroll
  for (int r = 0; r < 4; ++r) acc[r] = bv;

  for (int k4 = 0; k4 < 32; ++k4) {
    float4 xv[4];
#pragma unroll
    for (int r = 0; r < 4; ++r) xv[r] = sX4[(rg * 4 + r) * 32 + k4];
#pragma unroll
    for (int kk = 0; kk < 4; ++kk) {
      float4 wv = sW4[(k4 * 4 + kk) * C4 + cg];
#pragma unroll
      for (int r = 0; r < 4; ++r) {
        float x = (&xv[r].x)[kk];
        acc[r].x = fmaf(x, wv.x, acc[r].x);
        acc[r].y = fmaf(x, wv.y, acc[r].y);
        acc[r].z = fmaf(x, wv.z, acc[r].z);
        acc[r].w = fmaf(x, wv.w, acc[r].w);
      }
    }
  }

#pragma unroll
  for (int r = 0; r < 4; ++r) {
    int row = row0 + rg * 4 + r;
    if (row < M) {
      float4 v = acc[r];
      if (RELU) {
        v.x = fmaxf(v.x, 0.f); v.y = fmaxf(v.y, 0.f);
        v.z = fmaxf(v.z, 0.f); v.w = fmaxf(v.w, 0.f);
      }
      ((float4*)(O + (size_t)row * DOUT))[cg] = v;
    }
  }

  if (STATS) {
    float s[4] = {0.f, 0.f, 0.f, 0.f}, ss[4] = {0.f, 0.f, 0.f, 0.f};
#pragma unroll
    for (int r = 0; r < 4; ++r) {
      if (row0 + rg * 4 + r < M) {
#pragma unroll
        for (int j = 0; j < 4; ++j) {
          float v = (&acc[r].x)[j];
          s[j] += v;
          ss[j] += v * v;
        }
      }
    }
    __syncthreads();
    float* sSt = sX;
    for (int i = threadIdx.x; i < 2 * DOUT; i += 256) sSt[i] = 0.f;
    __syncthreads();
#pragma unroll
    for (int j = 0; j < 4; ++j) {
      atomicAdd(&sSt[cg * 4 + j], s[j]);
      atomicAdd(&sSt[DOUT + cg * 4 + j], ss[j]);
    }
    __syncthreads();
    for (int i = threadIdx.x; i < 2 * DOUT; i += 256) atomicAdd(&gstats[i], sSt[i]);
  }
}

// ---------------------------------------------------------------- BN finalize: stats -> scale/shift
template <int DOUT>
__global__ void finalize_stats_kernel(float* __restrict__ stats, const float* __restrict__ g,
                                      const float* __restrict__ be) {
  int c = threadIdx.x;
  if (c < DOUT) {
    float inv_n = 1.0f / (float)N_NODES;
    float mean = stats[c] * inv_n;
    float var = stats[DOUT + c] * inv_n - mean * mean;
    float sc = g[c] * rsqrtf(var + BN_EPS);
    stats[2 * DOUT + c] = sc;
    stats[3 * DOUT + c] = be[c] - mean * sc;
  }
}

// ---------------------------------------------------------------- segmented mean pool
// batch is sorted. Each block: POOL_CHUNK contiguous nodes; per-thread register
// run-accumulation (flush on graph transition) -> LDS per-graph table -> one
// global atomic pass for the block's spanned graph range. BN+ReLU fused.
__global__ __launch_bounds__(256) void pool_seg_kernel(
    const float* __restrict__ h, const float* __restrict__ scale,
    const float* __restrict__ shift, const int* __restrict__ batch,
    float* __restrict__ sums) {
  __shared__ float sacc[N_GRAPHS * 64];
  int tid = threadIdx.x;
  for (int i = tid; i < N_GRAPHS * 64; i += 256) sacc[i] = 0.f;

  int base = blockIdx.x * POOL_CHUNK;
  int last = min(base + POOL_CHUNK, N_NODES) - 1;
  int c4 = tid & 15;
  int r = tid >> 4;
  float4 sc = ((const float4*)scale)[c4];
  float4 sh = ((const float4*)shift)[c4];
  __syncthreads();

  float4 acc = make_float4(0.f, 0.f, 0.f, 0.f);
  int gcur = -1;
#pragma unroll 1
  for (int j = 0; j < POOL_CHUNK / 16; ++j) {
    int node = base + j * 16 + r;
    if (node >= N_NODES) break;
    int g = batch[node];
    if (g != gcur) {
      if (gcur >= 0) {
        float* p = &sacc[gcur * 64 + c4 * 4];
        atomicAdd(p + 0, acc.x); atomicAdd(p + 1, acc.y);
        atomicAdd(p + 2, acc.z); atomicAdd(p + 3, acc.w);
      }
      gcur = g;
      acc = make_float4(0.f, 0.f, 0.f, 0.f);
    }
    float4 v = ((const float4*)(h + (size_t)node * 64))[c4];
    v = bn_relu4v(v, sc, sh);
    acc.x += v.x; acc.y += v.y; acc.z += v.z; acc.w += v.w;
  }
  if (gcur >= 0) {
    float* p = &sacc[gcur * 64 + c4 * 4];
    atomicAdd(p + 0, acc.x); atomicAdd(p + 1, acc.y);
    atomicAdd(p + 2, acc.z); atomicAdd(p + 3, acc.w);
  }
  __syncthreads();

  int gmin = batch[base];
  int gmax = batch[last];
  for (int g = gmin; g <= gmax; ++g)
    for (int i = tid; i < 64; i += 256)
      atomicAdd(&sums[g * 64 + i], sacc[g * 64 + i]);
}

// ---------------------------------------------------------------- divide by counts (binary search, batch sorted)
__global__ __launch_bounds__(256) void div_kernel(const float* __restrict__ sums,
                                                  const int* __restrict__ batch,
                                                  float* __restrict__ out) {
  int i = blockIdx.x * blockDim.x + threadIdx.x;
  if (i >= N_GRAPHS * 64) return;
  int g = i >> 6;
  int lo = 0, hi = N_NODES;
  while (lo < hi) { int m = (lo + hi) >> 1; if (batch[m] < g) lo = m + 1; else hi = m; }
  int lb = lo;
  lo = 0; hi = N_NODES;
  while (lo < hi) { int m = (lo + hi) >> 1; if (batch[m] <= g) lo = m + 1; else hi = m; }
  float cnt = (float)(lo - lb);
  out[i] = sums[i] / fmaxf(cnt, 1.0f);
}

// ---------------------------------------------------------------- launch
extern "C" void kernel_launch(void* const* d_in, const int* in_sizes, int n_in,
                              void* d_out, int out_size, void* d_ws, size_t ws_size,
                              hipStream_t stream) {
  const float* x = (const float*)d_in[0];
  const int* edge_index = (const int*)d_in[1];
  const int* batch = (const int*)d_in[2];
  const int* src = edge_index;
  const int* dst = edge_index + N_EDGES;

  const float* wa[3] = {(const float*)d_in[3], (const float*)d_in[9],  (const float*)d_in[15]};
  const float* ba[3] = {(const float*)d_in[4], (const float*)d_in[10], (const float*)d_in[16]};
  const float* wb[3] = {(const float*)d_in[5], (const float*)d_in[11], (const float*)d_in[17]};
  const float* bb[3] = {(const float*)d_in[6], (const float*)d_in[12], (const float*)d_in[18]};
  const float* gg[3] = {(const float*)d_in[7], (const float*)d_in[13], (const float*)d_in[19]};
  const float* be[3] = {(const float*)d_in[8], (const float*)d_in[14], (const float*)d_in[20]};

  // workspace layout (floats first, then ints)
  float* buf0 = (float*)d_ws;                       // N*128
  float* buf1 = buf0 + (size_t)N_NODES * 128;       // N*128
  float* stats0 = buf1 + (size_t)N_NODES * 128;     // 512: sum, sumsq, scale, shift
  float* stats1 = stats0 + 512;                     // 512
  float* stats2 = stats1 + 512;                     // 256
  float* psums = stats2 + 256;                      // G*64
  size_t n_floats = (size_t)N_NODES * 256 + 512 + 512 + 256 + (size_t)N_GRAPHS * 64;
  int* row_ptr = (int*)(psums + (size_t)N_GRAPHS * 64);  // N+1
  int* deg = row_ptr + (N_NODES + 1);               // N (reused as cursor)
  int* adj = deg + N_NODES;                         // E
  size_t needed_base = n_floats * 4;
  size_t needed_csr = needed_base + ((size_t)(N_NODES + 1) + N_NODES + N_EDGES) * 4;
  if (ws_size < needed_base) return;
  bool use_csr = ws_size >= needed_csr;

  // zero stats + pool sums in one memset
  size_t zbytes = (512 + 512 + 256 + (size_t)N_GRAPHS * 64) * 4;
  hipMemsetAsync(stats0, 0, zbytes, stream);

  const int total4_128 = N_NODES * 32;
  const int copy_blocks = (total4_128 + 255) / 256;
  const int eb = (N_EDGES + 255) / 256;
  const int nb = (N_NODES + 255) / 256;
  const int gather_blocks = (N_NODES * 32 + 255) / 256;
  const int scat_blocks = (N_EDGES * 32) / 256;

  if (use_csr) {
    hipMemsetAsync(deg, 0, N_NODES * 4, stream);
    hist_kernel<<<eb, 256, 0, stream>>>(dst, deg);
    scan_kernel<<<1, 256, 0, stream>>>(deg, row_ptr);
    cursor_init_kernel<<<nb, 256, 0, stream>>>(row_ptr, deg);
    fill_kernel<<<eb, 256, 0, stream>>>(src, dst, deg, adj);
  }

  const float* in = x;
  float* bufs[2] = {buf0, buf1};
  float* stats[3] = {stats0, stats1, stats2};
  const int douts[3] = {128, 128, 64};
  const float* cur_scale = nullptr;  // BN params of the PREVIOUS layer (applied on read)
  const float* cur_shift = nullptr;

  for (int l = 0; l < 3; ++l) {
    float* agg = bufs[l & 1];
    float* mid = bufs[(l + 1) & 1];
    float* out = agg;  // mlp2 overwrites agg's buffer (agg already consumed by mlp1)
    if (use_csr) {
      if (l == 0)
        gather_agg_kernel<false><<<gather_blocks, 256, 0, stream>>>(in, nullptr, nullptr,
                                                                    row_ptr, adj, agg);
      else
        gather_agg_kernel<true><<<gather_blocks, 256, 0, stream>>>(in, cur_scale, cur_shift,
                                                                   row_ptr, adj, agg);
    } else {
      if (l == 0) {
        act_copy_kernel<false><<<copy_blocks, 256, 0, stream>>>(in, nullptr, nullptr, agg, total4_128);
        scatter_add_kernel<false><<<scat_blocks, 256, 0, stream>>>(in, nullptr, nullptr, src, dst, agg);
      } else {
        act_copy_kernel<true><<<copy_blocks, 256, 0, stream>>>(in, cur_scale, cur_shift, agg, total4_128);
        scatter_add_kernel<true><<<scat_blocks, 256, 0, stream>>>(in, cur_scale, cur_shift, src, dst, agg);
      }
    }
    mlp_kernel<128, true, false><<<3125, 256, 0, stream>>>(agg, wa[l], ba[l], mid, nullptr, N_NODES);
    if (douts[l] == 128) {
      mlp_kernel<128, false, true><<<3125, 256, 0, stream>>>(mid, wb[l], bb[l], out, stats[l], N_NODES);
      finalize_stats_kernel<128><<<1, 128, 0, stream>>>(stats[l], gg[l], be[l]);
      cur_scale = stats[l] + 256;
      cur_shift = stats[l] + 384;
    } else {
      mlp_kernel<64, false, true><<<1563, 256, 0, stream>>>(mid, wb[l], bb[l], out, stats[l], N_NODES);
      finalize_stats_kernel<64><<<1, 64, 0, stream>>>(stats[l], gg[l], be[l]);
      cur_scale = stats[l] + 128;
      cur_shift = stats[l] + 192;
    }
    in = out;  // pre-act h of this layer; BN+ReLU applied by next consumer
  }

  // segmented pool over pre-act h2 (N x 64), BN2+ReLU fused
  pool_seg_kernel<<<POOL_BLOCKS, 256, 0, stream>>>(in, cur_scale, cur_shift, batch, psums);
  div_kernel<<<32, 256, 0, stream>>>(psums, batch, (float*)d_out);
}

// Round 4
// 855.915 us; speedup vs baseline: 10.7509x; 1.5949x over previous
//
#include <hip/hip_runtime.h>

// GIN encoder: 3 x [CSR gather-agg bf16, MFMA MLP(128->128->D) bf16, BN-stats] + segmented mean-pool
// N=100000 nodes, E=1600000 edges, G=128 graphs.
// R4: hierarchical scan, bf16 activations, mfma_f32_16x16x32_bf16 MLPs (fp32 accumulate,
//     BN stats from fp32 accumulators), fragment-preordered weights (conflict-free LDS).

#define N_NODES 100000
#define N_EDGES 1600000
#define N_GRAPHS 128
#define BN_EPS 1e-5f
#define POOL_CHUNK 400
#define POOL_BLOCKS ((N_NODES + POOL_CHUNK - 1) / POOL_CHUNK)  // 250
#define PARTS ((N_NODES + 255) / 256)                          // 391

typedef __attribute__((ext_vector_type(8))) short bf16x8;
typedef __attribute__((ext_vector_type(4))) float f32x4;

// ---------------------------------------------------------------- bf16 helpers
__device__ __forceinline__ unsigned short rne16(float f) {
  unsigned u = __float_as_uint(f);
  u += 0x7fffu + ((u >> 16) & 1u);
  return (unsigned short)(u >> 16);
}
__device__ __forceinline__ unsigned pack2(float lo, float hi) {
  unsigned a = __float_as_uint(lo); a += 0x7fffu + ((a >> 16) & 1u);
  unsigned b = __float_as_uint(hi); b += 0x7fffu + ((b >> 16) & 1u);
  return (a >> 16) | (b & 0xffff0000u);
}
__device__ __forceinline__ void bf2_to_f32(unsigned u, float& lo, float& hi) {
  lo = __uint_as_float(u << 16);
  hi = __uint_as_float(u & 0xffff0000u);
}
__device__ __forceinline__ void bf8_to_f32(uint4 u, float* f) {
  bf2_to_f32(u.x, f[0], f[1]);
  bf2_to_f32(u.y, f[2], f[3]);
  bf2_to_f32(u.z, f[4], f[5]);
  bf2_to_f32(u.w, f[6], f[7]);
}

// ---------------------------------------------------------------- fp32 -> bf16 bulk convert (8/thread)
__global__ __launch_bounds__(256) void f2b_kernel(const float* __restrict__ x,
                                                  unsigned short* __restrict__ xb, int total8) {
  int i = blockIdx.x * 256 + threadIdx.x;
  if (i >= total8) return;
  const float4* p = (const float4*)x + (size_t)i * 2;
  float4 a = p[0], b = p[1];
  uint4 o;
  o.x = pack2(a.x, a.y); o.y = pack2(a.z, a.w);
  o.z = pack2(b.x, b.y); o.w = pack2(b.z, b.w);
  ((uint4*)xb)[i] = o;
}

// ---------------------------------------------------------------- weight prep: W(K=128 x N fp32) -> frag-ordered bf16
// flat = ((ntile*4 + kchunk)*64 + lane)*8 + j ; k = kchunk*32 + (lane>>4)*8 + j ; n = ntile*16 + (lane&15)
__global__ __launch_bounds__(256) void wprep_kernel(const float* __restrict__ W,
                                                    unsigned short* __restrict__ out, int N) {
  int f = blockIdx.x * 256 + threadIdx.x;
  if (f >= 128 * N) return;
  int j = f & 7;
  int lane = (f >> 3) & 63;
  int t = f >> 9;
  int kchunk = t & 3, ntile = t >> 2;
  int k = kchunk * 32 + (lane >> 4) * 8 + j;
  int n = ntile * 16 + (lane & 15);
  out[f] = rne16(W[k * N + n]);
}

// ---------------------------------------------------------------- CSR build
__global__ __launch_bounds__(256) void hist_kernel(const int* __restrict__ dst,
                                                   int* __restrict__ deg) {
  int e = blockIdx.x * 256 + threadIdx.x;
  if (e < N_EDGES) atomicAdd(&deg[dst[e]], 1);
}

__global__ __launch_bounds__(256) void partial_kernel(const int* __restrict__ deg,
                                                      int* __restrict__ part) {
  __shared__ int red[256];
  int tid = threadIdx.x;
  int i = blockIdx.x * 256 + tid;
  red[tid] = (i < N_NODES) ? deg[i] : 0;
  __syncthreads();
  for (int s = 128; s > 0; s >>= 1) {
    if (tid < s) red[tid] += red[tid + s];
    __syncthreads();
  }
  if (tid == 0) part[blockIdx.x] = red[0];
}

// scan of PARTS partials (inclusive, in place); also writes row_ptr[N]=E
__global__ __launch_bounds__(512) void offset_scan_kernel(int* __restrict__ part,
                                                          int* __restrict__ row_ptr) {
  __shared__ int tmp[512];
  int tid = threadIdx.x;
  tmp[tid] = (tid < PARTS) ? part[tid] : 0;
  __syncthreads();
  for (int off = 1; off < 512; off <<= 1) {
    int t = (tid >= off) ? tmp[tid - off] : 0;
    __syncthreads();
    tmp[tid] += t;
    __syncthreads();
  }
  if (tid < PARTS) part[tid] = tmp[tid];
  if (tid == 0) row_ptr[N_NODES] = N_EDGES;
}

__global__ __launch_bounds__(256) void final_scan_kernel(const int* __restrict__ deg,
                                                         const int* __restrict__ part,
                                                         int* __restrict__ row_ptr) {
  __shared__ int tmp[256];
  int tid = threadIdx.x;
  int i = blockIdx.x * 256 + tid;
  int v = (i < N_NODES) ? deg[i] : 0;
  tmp[tid] = v;
  __syncthreads();
  for (int off = 1; off < 256; off <<= 1) {
    int t = (tid >= off) ? tmp[tid - off] : 0;
    __syncthreads();
    tmp[tid] += t;
    __syncthreads();
  }
  int base = blockIdx.x ? part[blockIdx.x - 1] : 0;
  if (i < N_NODES) row_ptr[i] = base + tmp[tid] - v;
}

__global__ __launch_bounds__(256) void cursor_init_kernel(const int* __restrict__ row_ptr,
                                                          int* __restrict__ cursor) {
  int i = blockIdx.x * 256 + threadIdx.x;
  if (i < N_NODES) cursor[i] = row_ptr[i];
}

__global__ __launch_bounds__(256) void fill_kernel(const int* __restrict__ src,
                                                   const int* __restrict__ dst,
                                                   int* __restrict__ cursor,
                                                   int* __restrict__ adj) {
  int e = blockIdx.x * 256 + threadIdx.x;
  if (e < N_EDGES) {
    int pos = atomicAdd(&cursor[dst[e]], 1);
    adj[pos] = src[e];
  }
}

// ---------------------------------------------------------------- gather agg (bf16 in/out, fp32 accum)
// agg[n] = act(in[n]) + sum_{s in adj[n]} act(in[s]); 16 threads/node, 8 cols (16B) each.
template <bool BN>
__global__ __launch_bounds__(256) void gather_bf_kernel(
    const unsigned short* __restrict__ in, const float* __restrict__ scale,
    const float* __restrict__ shift, const int* __restrict__ row_ptr,
    const int* __restrict__ adj, unsigned short* __restrict__ agg) {
  int gid = blockIdx.x * 256 + threadIdx.x;
  int n = gid >> 4;
  if (n >= N_NODES) return;
  int c8 = gid & 15;
  float sc[8], sh[8];
  if (BN) {
    float4 s0 = ((const float4*)scale)[c8 * 2], s1 = ((const float4*)scale)[c8 * 2 + 1];
    float4 h0 = ((const float4*)shift)[c8 * 2], h1 = ((const float4*)shift)[c8 * 2 + 1];
    sc[0] = s0.x; sc[1] = s0.y; sc[2] = s0.z; sc[3] = s0.w;
    sc[4] = s1.x; sc[5] = s1.y; sc[6] = s1.z; sc[7] = s1.w;
    sh[0] = h0.x; sh[1] = h0.y; sh[2] = h0.z; sh[3] = h0.w;
    sh[4] = h1.x; sh[5] = h1.y; sh[6] = h1.z; sh[7] = h1.w;
  }
  int beg = row_ptr[n], end = row_ptr[n + 1];
  float acc[8];
  {
    uint4 u = ((const uint4*)(in + (size_t)n * 128))[c8];
    float f[8];
    bf8_to_f32(u, f);
#pragma unroll
    for (int j = 0; j < 8; ++j)
      acc[j] = BN ? fmaxf(fmaf(f[j], sc[j], sh[j]), 0.f) : f[j];
  }
  int k = beg;
  uint4 nxt;
  if (k < end) nxt = ((const uint4*)(in + (size_t)adj[k] * 128))[c8];
  while (k < end) {
    uint4 cur = nxt;
    ++k;
    if (k < end) nxt = ((const uint4*)(in + (size_t)adj[k] * 128))[c8];
    float f[8];
    bf8_to_f32(cur, f);
#pragma unroll
    for (int j = 0; j < 8; ++j)
      acc[j] += BN ? fmaxf(fmaf(f[j], sc[j], sh[j]), 0.f) : f[j];
  }
  uint4 o;
  o.x = pack2(acc[0], acc[1]); o.y = pack2(acc[2], acc[3]);
  o.z = pack2(acc[4], acc[5]); o.w = pack2(acc[6], acc[7]);
  ((uint4*)(agg + (size_t)n * 128))[c8] = o;
}

// ---------------------------------------------------------------- MFMA MLP: O = [relu](A @ W + b), bf16 in/out
// A: M x 128 bf16 row-major. Wf: frag-ordered bf16 (see wprep). Block = 4 waves x 16 rows.
// A-frag: A[m=lane&15][k=quad*8+j]; B-frag: W[k=quad*8+j][n=lane&15]; C/D: col=lane&15, row=quad*4+reg.
template <int N, bool RELU, bool STATS>
__global__ __launch_bounds__(256) void mlp_mfma_kernel(
    const unsigned short* __restrict__ A, const unsigned short* __restrict__ Wf,
    const float* __restrict__ bias, unsigned short* __restrict__ O,
    float* __restrict__ gstats, int M) {
  constexpr int NT = N / 16;
  __shared__ unsigned short sW[128 * N];
  __shared__ float sSt[STATS ? 2 * N : 1];

  {
    const uint4* s = (const uint4*)Wf;
    uint4* d = (uint4*)sW;
    for (int i = threadIdx.x; i < 128 * N / 8; i += 256) d[i] = s[i];
  }
  __syncthreads();

  int lane = threadIdx.x & 63;
  int wave = threadIdx.x >> 6;
  int m = lane & 15, quad = lane >> 4;
  int row0w = blockIdx.x * 64 + wave * 16;
  int row = row0w + m;

  bf16x8 a[4];
  if (row < M) {
    const bf16x8* Ar = (const bf16x8*)(A + (size_t)row * 128);
#pragma unroll
    for (int kc = 0; kc < 4; ++kc) a[kc] = Ar[kc * 4 + quad];
  } else {
#pragma unroll
    for (int kc = 0; kc < 4; ++kc)
#pragma unroll
      for (int j = 0; j < 8; ++j) a[kc][j] = 0;
  }

  f32x4 acc[NT];
#pragma unroll
  for (int nt = 0; nt < NT; ++nt) {
    float bv = bias[nt * 16 + m];
#pragma unroll
    for (int r = 0; r < 4; ++r) acc[nt][r] = bv;
  }

  const bf16x8* sW8 = (const bf16x8*)sW;
#pragma unroll
  for (int kc = 0; kc < 4; ++kc) {
#pragma unroll
    for (int nt = 0; nt < NT; ++nt)
      acc[nt] = __builtin_amdgcn_mfma_f32_16x16x32_bf16(a[kc], sW8[(nt * 4 + kc) * 64 + lane],
                                                        acc[nt], 0, 0, 0);
  }

#pragma unroll
  for (int nt = 0; nt < NT; ++nt) {
#pragma unroll
    for (int r = 0; r < 4; ++r) {
      int grow = row0w + quad * 4 + r;
      if (grow < M) {
        float v = acc[nt][r];
        if (RELU) v = fmaxf(v, 0.f);
        O[(size_t)grow * N + nt * 16 + m] = rne16(v);
      }
    }
  }

  if (STATS) {
    for (int i = threadIdx.x; i < 2 * N; i += 256) sSt[i] = 0.f;
    __syncthreads();
#pragma unroll
    for (int nt = 0; nt < NT; ++nt) {
      float s = 0.f, ss = 0.f;
#pragma unroll
      for (int r = 0; r < 4; ++r) {
        if (row0w + quad * 4 + r < M) {
          float v = acc[nt][r];
          s += v;
          ss += v * v;
        }
      }
      atomicAdd(&sSt[nt * 16 + m], s);
      atomicAdd(&sSt[N + nt * 16 + m], ss);
    }
    __syncthreads();
    for (int i = threadIdx.x; i < 2 * N; i += 256) atomicAdd(&gstats[i], sSt[i]);
  }
}

// ---------------------------------------------------------------- BN finalize: stats -> scale/shift
template <int DOUT>
__global__ void finalize_stats_kernel(float* __restrict__ stats, const float* __restrict__ g,
                                      const float* __restrict__ be) {
  int c = threadIdx.x;
  if (c < DOUT) {
    float inv_n = 1.0f / (float)N_NODES;
    float mean = stats[c] * inv_n;
    float var = stats[DOUT + c] * inv_n - mean * mean;
    float sc = g[c] * rsqrtf(var + BN_EPS);
    stats[2 * DOUT + c] = sc;
    stats[3 * DOUT + c] = be[c] - mean * sc;
  }
}

// ---------------------------------------------------------------- segmented mean pool (bf16 in, BN+ReLU fused)
__global__ __launch_bounds__(256) void pool_seg_kernel(
    const unsigned short* __restrict__ h, const float* __restrict__ scale,
    const float* __restrict__ shift, const int* __restrict__ batch,
    float* __restrict__ sums) {
  __shared__ float sacc[N_GRAPHS * 64];
  int tid = threadIdx.x;
  for (int i = tid; i < N_GRAPHS * 64; i += 256) sacc[i] = 0.f;

  int base = blockIdx.x * POOL_CHUNK;
  int last = min(base + POOL_CHUNK, N_NODES) - 1;
  int c4 = tid & 15;
  int r = tid >> 4;
  float4 sc = ((const float4*)scale)[c4];
  float4 sh = ((const float4*)shift)[c4];
  __syncthreads();

  float4 acc = make_float4(0.f, 0.f, 0.f, 0.f);
  int gcur = -1;
#pragma unroll 1
  for (int j = 0; j < POOL_CHUNK / 16; ++j) {
    int node = base + j * 16 + r;
    if (node >= N_NODES) break;
    int g = batch[node];
    if (g != gcur) {
      if (gcur >= 0) {
        float* p = &sacc[gcur * 64 + c4 * 4];
        atomicAdd(p + 0, acc.x); atomicAdd(p + 1, acc.y);
        atomicAdd(p + 2, acc.z); atomicAdd(p + 3, acc.w);
      }
      gcur = g;
      acc = make_float4(0.f, 0.f, 0.f, 0.f);
    }
    uint2 u = ((const uint2*)(h + (size_t)node * 64))[c4];
    float f0, f1, f2, f3;
    bf2_to_f32(u.x, f0, f1);
    bf2_to_f32(u.y, f2, f3);
    acc.x += fmaxf(fmaf(f0, sc.x, sh.x), 0.f);
    acc.y += fmaxf(fmaf(f1, sc.y, sh.y), 0.f);
    acc.z += fmaxf(fmaf(f2, sc.z, sh.z), 0.f);
    acc.w += fmaxf(fmaf(f3, sc.w, sh.w), 0.f);
  }
  if (gcur >= 0) {
    float* p = &sacc[gcur * 64 + c4 * 4];
    atomicAdd(p + 0, acc.x); atomicAdd(p + 1, acc.y);
    atomicAdd(p + 2, acc.z); atomicAdd(p + 3, acc.w);
  }
  __syncthreads();

  int gmin = batch[base];
  int gmax = batch[last];
  for (int g = gmin; g <= gmax; ++g)
    for (int i = tid; i < 64; i += 256)
      atomicAdd(&sums[g * 64 + i], sacc[g * 64 + i]);
}

// ---------------------------------------------------------------- divide by counts (binary search)
__global__ __launch_bounds__(256) void div_kernel(const float* __restrict__ sums,
                                                  const int* __restrict__ batch,
                                                  float* __restrict__ out) {
  int i = blockIdx.x * blockDim.x + threadIdx.x;
  if (i >= N_GRAPHS * 64) return;
  int g = i >> 6;
  int lo = 0, hi = N_NODES;
  while (lo < hi) { int m = (lo + hi) >> 1; if (batch[m] < g) lo = m + 1; else hi = m; }
  int lb = lo;
  lo = 0; hi = N_NODES;
  while (lo < hi) { int m = (lo + hi) >> 1; if (batch[m] <= g) lo = m + 1; else hi = m; }
  float cnt = (float)(lo - lb);
  out[i] = sums[i] / fmaxf(cnt, 1.0f);
}

// ---------------------------------------------------------------- launch
extern "C" void kernel_launch(void* const* d_in, const int* in_sizes, int n_in,
                              void* d_out, int out_size, void* d_ws, size_t ws_size,
                              hipStream_t stream) {
  const float* x = (const float*)d_in[0];
  const int* edge_index = (const int*)d_in[1];
  const int* batch = (const int*)d_in[2];
  const int* src = edge_index;
  const int* dst = edge_index + N_EDGES;

  const float* wa[3] = {(const float*)d_in[3], (const float*)d_in[9],  (const float*)d_in[15]};
  const float* ba[3] = {(const float*)d_in[4], (const float*)d_in[10], (const float*)d_in[16]};
  const float* wb[3] = {(const float*)d_in[5], (const float*)d_in[11], (const float*)d_in[17]};
  const float* bb[3] = {(const float*)d_in[6], (const float*)d_in[12], (const float*)d_in[18]};
  const float* gg[3] = {(const float*)d_in[7], (const float*)d_in[13], (const float*)d_in[19]};
  const float* be[3] = {(const float*)d_in[8], (const float*)d_in[14], (const float*)d_in[20]};

  // -------- workspace layout --------
  // fp32: stats0(512) stats1(512) stats2(256) psums(8192)  -> 9472 floats, zeroed each call
  float* stats0 = (float*)d_ws;
  float* stats1 = stats0 + 512;
  float* stats2 = stats1 + 512;
  float* psums = stats2 + 256;
  // int: row_ptr(N+1) deg(N) part(PARTS, pad to even) adj(E)
  int* row_ptr = (int*)(psums + (size_t)N_GRAPHS * 64);
  int* deg = row_ptr + (N_NODES + 1);
  int* part = deg + N_NODES;
  int* adj = part + ((PARTS + 3) & ~3);
  // u16: xb, b0, b1 (N*128 each), wfrag 6 x 16384
  unsigned short* xb = (unsigned short*)(adj + N_EDGES);
  unsigned short* b0 = xb + (size_t)N_NODES * 128;
  unsigned short* b1 = b0 + (size_t)N_NODES * 128;
  unsigned short* wf[6];
  for (int i = 0; i < 6; ++i) wf[i] = b1 + (size_t)N_NODES * 128 + (size_t)i * 16384;
  size_t needed = (size_t)((unsigned short*)wf[5] + 16384 - (unsigned short*)d_ws) * 2;
  if (ws_size < needed) return;

  hipMemsetAsync(stats0, 0, 9472 * 4, stream);
  hipMemsetAsync(deg, 0, N_NODES * 4, stream);

  const int eb = (N_EDGES + 255) / 256;
  const int nb = (N_NODES + 255) / 256;

  // weight prep (wa: 128x128, wb: 128x{128,128,64})
  wprep_kernel<<<64, 256, 0, stream>>>(wa[0], wf[0], 128);
  wprep_kernel<<<64, 256, 0, stream>>>(wb[0], wf[1], 128);
  wprep_kernel<<<64, 256, 0, stream>>>(wa[1], wf[2], 128);
  wprep_kernel<<<64, 256, 0, stream>>>(wb[1], wf[3], 128);
  wprep_kernel<<<64, 256, 0, stream>>>(wa[2], wf[4], 128);
  wprep_kernel<<<32, 256, 0, stream>>>(wb[2], wf[5], 64);

  // x -> bf16
  f2b_kernel<<<(N_NODES * 16 + 255) / 256, 256, 0, stream>>>(x, xb, N_NODES * 16);

  // CSR build
  hist_kernel<<<eb, 256, 0, stream>>>(dst, deg);
  partial_kernel<<<PARTS, 256, 0, stream>>>(deg, part);
  offset_scan_kernel<<<1, 512, 0, stream>>>(part, row_ptr);
  final_scan_kernel<<<PARTS, 256, 0, stream>>>(deg, part, row_ptr);
  cursor_init_kernel<<<nb, 256, 0, stream>>>(row_ptr, deg);  // deg becomes cursor
  fill_kernel<<<eb, 256, 0, stream>>>(src, dst, deg, adj);

  const int gather_blocks = (N_NODES * 16 + 255) / 256;
  const int mlp_blocks = (N_NODES + 63) / 64;  // 1563

  // buffers per layer: l0: in=xb agg=b0 mid=b1 out=b0 ; l1: in=b0 agg=b1 mid=xb out=b1 ;
  //                    l2: in=b1 agg=b0 mid=xb out=b0
  float* stats[3] = {stats0, stats1, stats2};

  // ---- layer 0
  gather_bf_kernel<false><<<gather_blocks, 256, 0, stream>>>(xb, nullptr, nullptr, row_ptr, adj, b0);
  mlp_mfma_kernel<128, true, false><<<mlp_blocks, 256, 0, stream>>>(b0, wf[0], ba[0], b1, nullptr, N_NODES);
  mlp_mfma_kernel<128, false, true><<<mlp_blocks, 256, 0, stream>>>(b1, wf[1], bb[0], b0, stats0, N_NODES);
  finalize_stats_kernel<128><<<1, 128, 0, stream>>>(stats0, gg[0], be[0]);

  // ---- layer 1
  gather_bf_kernel<true><<<gather_blocks, 256, 0, stream>>>(b0, stats0 + 256, stats0 + 384,
                                                            row_ptr, adj, b1);
  mlp_mfma_kernel<128, true, false><<<mlp_blocks, 256, 0, stream>>>(b1, wf[2], ba[1], xb, nullptr, N_NODES);
  mlp_mfma_kernel<128, false, true><<<mlp_blocks, 256, 0, stream>>>(xb, wf[3], bb[1], b1, stats1, N_NODES);
  finalize_stats_kernel<128><<<1, 128, 0, stream>>>(stats1, gg[1], be[1]);

  // ---- layer 2
  gather_bf_kernel<true><<<gather_blocks, 256, 0, stream>>>(b1, stats1 + 256, stats1 + 384,
                                                            row_ptr, adj, b0);
  mlp_mfma_kernel<128, true, false><<<mlp_blocks, 256, 0, stream>>>(b0, wf[4], ba[2], xb, nullptr, N_NODES);
  mlp_mfma_kernel<64, false, true><<<mlp_blocks, 256, 0, stream>>>(xb, wf[5], bb[2], b0, stats2, N_NODES);
  finalize_stats_kernel<64><<<1, 64, 0, stream>>>(stats2, gg[2], be[2]);

  // ---- pool (BN2+ReLU fused) + divide
  pool_seg_kernel<<<POOL_BLOCKS, 256, 0, stream>>>(b0, stats2 + 128, stats2 + 192, batch, psums);
  div_kernel<<<32, 256, 0, stream>>>(psums, batch, (float*)d_out);
}

// Round 5
// 736.991 us; speedup vs baseline: 12.4857x; 1.1614x over previous
//
#include <hip/hip_runtime.h>

// GIN encoder: 3 x [CSR gather-agg bf16, MFMA MLP(128->128->D) bf16, BN-stats] + segmented mean-pool
// N=100000 nodes, E=1600000 edges, G=128 graphs.
// R5: bucketed CSR build (bucket = dst>>9): localized scatter writes kill the 16x
//     write amplification of the random fill; deg from per-bucket LDS histograms;
//     layer-0 gather reads fp32 x directly (f2b pass deleted); single wprep launch.

#define N_NODES 100000
#define N_EDGES 1600000
#define N_GRAPHS 128
#define BN_EPS 1e-5f
#define POOL_CHUNK 400
#define POOL_BLOCKS ((N_NODES + POOL_CHUNK - 1) / POOL_CHUNK)  // 250
#define PARTS ((N_NODES + 255) / 256)                          // 391
#define NBUCKETS ((N_NODES + 511) / 512)                       // 196
#define PSC_CHUNK 4096
#define PSC_BLOCKS ((N_EDGES + PSC_CHUNK - 1) / PSC_CHUNK)     // 391

typedef __attribute__((ext_vector_type(8))) short bf16x8;
typedef __attribute__((ext_vector_type(4))) float f32x4;

// ---------------------------------------------------------------- bf16 helpers
__device__ __forceinline__ unsigned short rne16(float f) {
  unsigned u = __float_as_uint(f);
  u += 0x7fffu + ((u >> 16) & 1u);
  return (unsigned short)(u >> 16);
}
__device__ __forceinline__ unsigned pack2(float lo, float hi) {
  unsigned a = __float_as_uint(lo); a += 0x7fffu + ((a >> 16) & 1u);
  unsigned b = __float_as_uint(hi); b += 0x7fffu + ((b >> 16) & 1u);
  return (a >> 16) | (b & 0xffff0000u);
}
__device__ __forceinline__ void bf2_to_f32(unsigned u, float& lo, float& hi) {
  lo = __uint_as_float(u << 16);
  hi = __uint_as_float(u & 0xffff0000u);
}
__device__ __forceinline__ void bf8_to_f32(uint4 u, float* f) {
  bf2_to_f32(u.x, f[0], f[1]);
  bf2_to_f32(u.y, f[2], f[3]);
  bf2_to_f32(u.z, f[4], f[5]);
  bf2_to_f32(u.w, f[6], f[7]);
}

// ---------------------------------------------------------------- weight prep (all 6 in one launch)
// W(K=128 x N fp32) -> frag-ordered bf16:
// flat = ((ntile*4 + kchunk)*64 + lane)*8 + j ; k = kchunk*32 + (lane>>4)*8 + j ; n = ntile*16 + (lane&15)
struct WPArgs {
  const float* w[6];
  unsigned short* o[6];
};
__global__ __launch_bounds__(256) void wprep_all_kernel(WPArgs wp) {
  int blk = blockIdx.x;
  int seg = (blk < 320) ? (blk >> 6) : 5;
  int base = (seg < 5) ? (seg << 6) : 320;
  int N = (seg == 5) ? 64 : 128;
  int f = (blk - base) * 256 + threadIdx.x;
  if (f >= 128 * N) return;
  int j = f & 7;
  int lane = (f >> 3) & 63;
  int t = f >> 9;
  int kchunk = t & 3, ntile = t >> 2;
  int k = kchunk * 32 + (lane >> 4) * 8 + j;
  int n = ntile * 16 + (lane & 15);
  wp.o[seg][f] = rne16(wp.w[seg][k * N + n]);
}

// ---------------------------------------------------------------- bucketed CSR build
// bucket = dst >> 9 (512 nodes per bucket)
__global__ __launch_bounds__(256) void bcount_kernel(const int* __restrict__ dst,
                                                     int* __restrict__ bcnt) {
  __shared__ int hist[NBUCKETS];
  int tid = threadIdx.x;
  for (int i = tid; i < NBUCKETS; i += 256) hist[i] = 0;
  __syncthreads();
  int e0 = blockIdx.x * PSC_CHUNK;
  int e1 = min(e0 + PSC_CHUNK, N_EDGES);
  for (int e = e0 + tid; e < e1; e += 256) atomicAdd(&hist[dst[e] >> 9], 1);
  __syncthreads();
  for (int i = tid; i < NBUCKETS; i += 256)
    if (hist[i]) atomicAdd(&bcnt[i], hist[i]);
}

__global__ __launch_bounds__(256) void bscan_kernel(const int* __restrict__ bcnt,
                                                    int* __restrict__ boff,
                                                    int* __restrict__ bcur) {
  __shared__ int tmp[256];
  int tid = threadIdx.x;
  int c = (tid < NBUCKETS) ? bcnt[tid] : 0;
  tmp[tid] = c;
  __syncthreads();
  for (int off = 1; off < 256; off <<= 1) {
    int t = (tid >= off) ? tmp[tid - off] : 0;
    __syncthreads();
    tmp[tid] += t;
    __syncthreads();
  }
  if (tid < NBUCKETS) {
    int s = tmp[tid] - c;  // exclusive
    boff[tid] = s;
    bcur[tid] = s;
  }
  if (tid == 0) boff[NBUCKETS] = N_EDGES;
}

// block-aggregated pair scatter: pairs[pos] = (src<<9)|local_dst, grouped by bucket
__global__ __launch_bounds__(256) void pscatter_kernel(const int* __restrict__ src,
                                                       const int* __restrict__ dst,
                                                       int* __restrict__ bcur,
                                                       unsigned* __restrict__ pairs) {
  __shared__ int hist[NBUCKETS];
  __shared__ int base[NBUCKETS];
  int tid = threadIdx.x;
  for (int i = tid; i < NBUCKETS; i += 256) hist[i] = 0;
  __syncthreads();
  int e0 = blockIdx.x * PSC_CHUNK;
  int e1 = min(e0 + PSC_CHUNK, N_EDGES);
  for (int e = e0 + tid; e < e1; e += 256) atomicAdd(&hist[dst[e] >> 9], 1);
  __syncthreads();
  for (int i = tid; i < NBUCKETS; i += 256) {
    int c = hist[i];
    base[i] = c ? atomicAdd(&bcur[i], c) : 0;
    hist[i] = 0;  // becomes local cursor
  }
  __syncthreads();
  for (int e = e0 + tid; e < e1; e += 256) {
    int d = dst[e];
    int b = d >> 9;
    int slot = atomicAdd(&hist[b], 1);
    pairs[base[b] + slot] = ((unsigned)src[e] << 9) | (unsigned)(d & 511);
  }
}

// per-bucket degree via LDS histogram -> clean sequential deg write
__global__ __launch_bounds__(256) void bdeg_kernel(const unsigned* __restrict__ pairs,
                                                   const int* __restrict__ boff,
                                                   int* __restrict__ deg) {
  __shared__ int h[512];
  int tid = threadIdx.x, b = blockIdx.x;
  for (int i = tid; i < 512; i += 256) h[i] = 0;
  __syncthreads();
  int p0 = boff[b], p1 = boff[b + 1];
  for (int p = p0 + tid; p < p1; p += 256) atomicAdd(&h[pairs[p] & 511u], 1);
  __syncthreads();
  int n0 = b << 9;
  for (int i = tid; i < 512; i += 256)
    if (n0 + i < N_NODES) deg[n0 + i] = h[i];
}

// per-bucket CSR fill: writes land in the bucket's contiguous adj region (L2-resident)
__global__ __launch_bounds__(256) void bfill_kernel(const unsigned* __restrict__ pairs,
                                                    const int* __restrict__ boff,
                                                    const int* __restrict__ row_ptr,
                                                    int* __restrict__ adj) {
  __shared__ int cur[512];
  int tid = threadIdx.x, b = blockIdx.x;
  int n0 = b << 9;
  for (int i = tid; i < 512; i += 256)
    cur[i] = (n0 + i < N_NODES) ? row_ptr[n0 + i] : 0;
  __syncthreads();
  int p0 = boff[b], p1 = boff[b + 1];
  for (int p = p0 + tid; p < p1; p += 256) {
    unsigned pr = pairs[p];
    int pos = atomicAdd(&cur[pr & 511u], 1);
    adj[pos] = (int)(pr >> 9);
  }
}

// ---------------------------------------------------------------- row_ptr hierarchical scan
__global__ __launch_bounds__(256) void partial_kernel(const int* __restrict__ deg,
                                                      int* __restrict__ part) {
  __shared__ int red[256];
  int tid = threadIdx.x;
  int i = blockIdx.x * 256 + tid;
  red[tid] = (i < N_NODES) ? deg[i] : 0;
  __syncthreads();
  for (int s = 128; s > 0; s >>= 1) {
    if (tid < s) red[tid] += red[tid + s];
    __syncthreads();
  }
  if (tid == 0) part[blockIdx.x] = red[0];
}

__global__ __launch_bounds__(512) void offset_scan_kernel(int* __restrict__ part,
                                                          int* __restrict__ row_ptr) {
  __shared__ int tmp[512];
  int tid = threadIdx.x;
  tmp[tid] = (tid < PARTS) ? part[tid] : 0;
  __syncthreads();
  for (int off = 1; off < 512; off <<= 1) {
    int t = (tid >= off) ? tmp[tid - off] : 0;
    __syncthreads();
    tmp[tid] += t;
    __syncthreads();
  }
  if (tid < PARTS) part[tid] = tmp[tid];
  if (tid == 0) row_ptr[N_NODES] = N_EDGES;
}

__global__ __launch_bounds__(256) void final_scan_kernel(const int* __restrict__ deg,
                                                         const int* __restrict__ part,
                                                         int* __restrict__ row_ptr) {
  __shared__ int tmp[256];
  int tid = threadIdx.x;
  int i = blockIdx.x * 256 + tid;
  int v = (i < N_NODES) ? deg[i] : 0;
  tmp[tid] = v;
  __syncthreads();
  for (int off = 1; off < 256; off <<= 1) {
    int t = (tid >= off) ? tmp[tid - off] : 0;
    __syncthreads();
    tmp[tid] += t;
    __syncthreads();
  }
  int base = blockIdx.x ? part[blockIdx.x - 1] : 0;
  if (i < N_NODES) row_ptr[i] = base + tmp[tid] - v;
}

// ---------------------------------------------------------------- gather agg (fp32 or bf16 in, bf16 out)
// agg[n] = act(in[n]) + sum_{s in adj[n]} act(in[s]); 16 threads/node, 8 cols each.
template <bool BN, typename TIN>
__global__ __launch_bounds__(256) void gather_kernel(
    const TIN* __restrict__ in, const float* __restrict__ scale,
    const float* __restrict__ shift, const int* __restrict__ row_ptr,
    const int* __restrict__ adj, unsigned short* __restrict__ agg) {
  int gid = blockIdx.x * 256 + threadIdx.x;
  int n = gid >> 4;
  if (n >= N_NODES) return;
  int c8 = gid & 15;
  float sc[8], sh[8];
  if (BN) {
    float4 s0 = ((const float4*)scale)[c8 * 2], s1 = ((const float4*)scale)[c8 * 2 + 1];
    float4 h0 = ((const float4*)shift)[c8 * 2], h1 = ((const float4*)shift)[c8 * 2 + 1];
    sc[0] = s0.x; sc[1] = s0.y; sc[2] = s0.z; sc[3] = s0.w;
    sc[4] = s1.x; sc[5] = s1.y; sc[6] = s1.z; sc[7] = s1.w;
    sh[0] = h0.x; sh[1] = h0.y; sh[2] = h0.z; sh[3] = h0.w;
    sh[4] = h1.x; sh[5] = h1.y; sh[6] = h1.z; sh[7] = h1.w;
  }
  auto load8 = [&](int node, float* f) {
    if constexpr (sizeof(TIN) == 2) {
      uint4 u = ((const uint4*)((const unsigned short*)in + (size_t)node * 128))[c8];
      bf8_to_f32(u, f);
    } else {
      const float4* p = (const float4*)((const float*)in + (size_t)node * 128) + c8 * 2;
      float4 a = p[0], b = p[1];
      f[0] = a.x; f[1] = a.y; f[2] = a.z; f[3] = a.w;
      f[4] = b.x; f[5] = b.y; f[6] = b.z; f[7] = b.w;
    }
  };
  int beg = row_ptr[n], end = row_ptr[n + 1];
  float acc[8], f[8];
  load8(n, f);
#pragma unroll
  for (int j = 0; j < 8; ++j)
    acc[j] = BN ? fmaxf(fmaf(f[j], sc[j], sh[j]), 0.f) : f[j];
  for (int k = beg; k < end; ++k) {
    load8(adj[k], f);
#pragma unroll
    for (int j = 0; j < 8; ++j)
      acc[j] += BN ? fmaxf(fmaf(f[j], sc[j], sh[j]), 0.f) : f[j];
  }
  uint4 o;
  o.x = pack2(acc[0], acc[1]); o.y = pack2(acc[2], acc[3]);
  o.z = pack2(acc[4], acc[5]); o.w = pack2(acc[6], acc[7]);
  ((uint4*)(agg + (size_t)n * 128))[c8] = o;
}

// ---------------------------------------------------------------- MFMA MLP: O = [relu](A @ W + b), bf16 in/out
template <int N, bool RELU, bool STATS>
__global__ __launch_bounds__(256) void mlp_mfma_kernel(
    const unsigned short* __restrict__ A, const unsigned short* __restrict__ Wf,
    const float* __restrict__ bias, unsigned short* __restrict__ O,
    float* __restrict__ gstats, int M) {
  constexpr int NT = N / 16;
  __shared__ unsigned short sW[128 * N];
  __shared__ float sSt[STATS ? 2 * N : 1];

  {
    const uint4* s = (const uint4*)Wf;
    uint4* d = (uint4*)sW;
    for (int i = threadIdx.x; i < 128 * N / 8; i += 256) d[i] = s[i];
  }
  __syncthreads();

  int lane = threadIdx.x & 63;
  int wave = threadIdx.x >> 6;
  int m = lane & 15, quad = lane >> 4;
  int row0w = blockIdx.x * 64 + wave * 16;
  int row = row0w + m;

  bf16x8 a[4];
  if (row < M) {
    const bf16x8* Ar = (const bf16x8*)(A + (size_t)row * 128);
#pragma unroll
    for (int kc = 0; kc < 4; ++kc) a[kc] = Ar[kc * 4 + quad];
  } else {
#pragma unroll
    for (int kc = 0; kc < 4; ++kc)
#pragma unroll
      for (int j = 0; j < 8; ++j) a[kc][j] = 0;
  }

  f32x4 acc[NT];
#pragma unroll
  for (int nt = 0; nt < NT; ++nt) {
    float bv = bias[nt * 16 + m];
#pragma unroll
    for (int r = 0; r < 4; ++r) acc[nt][r] = bv;
  }

  const bf16x8* sW8 = (const bf16x8*)sW;
#pragma unroll
  for (int kc = 0; kc < 4; ++kc) {
#pragma unroll
    for (int nt = 0; nt < NT; ++nt)
      acc[nt] = __builtin_amdgcn_mfma_f32_16x16x32_bf16(a[kc], sW8[(nt * 4 + kc) * 64 + lane],
                                                        acc[nt], 0, 0, 0);
  }

#pragma unroll
  for (int nt = 0; nt < NT; ++nt) {
#pragma unroll
    for (int r = 0; r < 4; ++r) {
      int grow = row0w + quad * 4 + r;
      if (grow < M) {
        float v = acc[nt][r];
        if (RELU) v = fmaxf(v, 0.f);
        O[(size_t)grow * N + nt * 16 + m] = rne16(v);
      }
    }
  }

  if (STATS) {
    for (int i = threadIdx.x; i < 2 * N; i += 256) sSt[i] = 0.f;
    __syncthreads();
#pragma unroll
    for (int nt = 0; nt < NT; ++nt) {
      float s = 0.f, ss = 0.f;
#pragma unroll
      for (int r = 0; r < 4; ++r) {
        if (row0w + quad * 4 + r < M) {
          float v = acc[nt][r];
          s += v;
          ss += v * v;
        }
      }
      atomicAdd(&sSt[nt * 16 + m], s);
      atomicAdd(&sSt[N + nt * 16 + m], ss);
    }
    __syncthreads();
    for (int i = threadIdx.x; i < 2 * N; i += 256) atomicAdd(&gstats[i], sSt[i]);
  }
}

// ---------------------------------------------------------------- BN finalize: stats -> scale/shift
template <int DOUT>
__global__ void finalize_stats_kernel(float* __restrict__ stats, const float* __restrict__ g,
                                      const float* __restrict__ be) {
  int c = threadIdx.x;
  if (c < DOUT) {
    float inv_n = 1.0f / (float)N_NODES;
    float mean = stats[c] * inv_n;
    float var = stats[DOUT + c] * inv_n - mean * mean;
    float sc = g[c] * rsqrtf(var + BN_EPS);
    stats[2 * DOUT + c] = sc;
    stats[3 * DOUT + c] = be[c] - mean * sc;
  }
}

// ---------------------------------------------------------------- segmented mean pool (bf16 in, BN+ReLU fused)
__global__ __launch_bounds__(256) void pool_seg_kernel(
    const unsigned short* __restrict__ h, const float* __restrict__ scale,
    const float* __restrict__ shift, const int* __restrict__ batch,
    float* __restrict__ sums) {
  __shared__ float sacc[N_GRAPHS * 64];
  int tid = threadIdx.x;
  for (int i = tid; i < N_GRAPHS * 64; i += 256) sacc[i] = 0.f;

  int base = blockIdx.x * POOL_CHUNK;
  int last = min(base + POOL_CHUNK, N_NODES) - 1;
  int c4 = tid & 15;
  int r = tid >> 4;
  float4 sc = ((const float4*)scale)[c4];
  float4 sh = ((const float4*)shift)[c4];
  __syncthreads();

  float4 acc = make_float4(0.f, 0.f, 0.f, 0.f);
  int gcur = -1;
#pragma unroll 1
  for (int j = 0; j < POOL_CHUNK / 16; ++j) {
    int node = base + j * 16 + r;
    if (node >= N_NODES) break;
    int g = batch[node];
    if (g != gcur) {
      if (gcur >= 0) {
        float* p = &sacc[gcur * 64 + c4 * 4];
        atomicAdd(p + 0, acc.x); atomicAdd(p + 1, acc.y);
        atomicAdd(p + 2, acc.z); atomicAdd(p + 3, acc.w);
      }
      gcur = g;
      acc = make_float4(0.f, 0.f, 0.f, 0.f);
    }
    uint2 u = ((const uint2*)(h + (size_t)node * 64))[c4];
    float f0, f1, f2, f3;
    bf2_to_f32(u.x, f0, f1);
    bf2_to_f32(u.y, f2, f3);
    acc.x += fmaxf(fmaf(f0, sc.x, sh.x), 0.f);
    acc.y += fmaxf(fmaf(f1, sc.y, sh.y), 0.f);
    acc.z += fmaxf(fmaf(f2, sc.z, sh.z), 0.f);
    acc.w += fmaxf(fmaf(f3, sc.w, sh.w), 0.f);
  }
  if (gcur >= 0) {
    float* p = &sacc[gcur * 64 + c4 * 4];
    atomicAdd(p + 0, acc.x); atomicAdd(p + 1, acc.y);
    atomicAdd(p + 2, acc.z); atomicAdd(p + 3, acc.w);
  }
  __syncthreads();

  int gmin = batch[base];
  int gmax = batch[last];
  for (int g = gmin; g <= gmax; ++g)
    for (int i = tid; i < 64; i += 256)
      atomicAdd(&sums[g * 64 + i], sacc[g * 64 + i]);
}

// ---------------------------------------------------------------- divide by counts (binary search)
__global__ __launch_bounds__(256) void div_kernel(const float* __restrict__ sums,
                                                  const int* __restrict__ batch,
                                                  float* __restrict__ out) {
  int i = blockIdx.x * blockDim.x + threadIdx.x;
  if (i >= N_GRAPHS * 64) return;
  int g = i >> 6;
  int lo = 0, hi = N_NODES;
  while (lo < hi) { int m = (lo + hi) >> 1; if (batch[m] < g) lo = m + 1; else hi = m; }
  int lb = lo;
  lo = 0; hi = N_NODES;
  while (lo < hi) { int m = (lo + hi) >> 1; if (batch[m] <= g) lo = m + 1; else hi = m; }
  float cnt = (float)(lo - lb);
  out[i] = sums[i] / fmaxf(cnt, 1.0f);
}

// ---------------------------------------------------------------- launch
extern "C" void kernel_launch(void* const* d_in, const int* in_sizes, int n_in,
                              void* d_out, int out_size, void* d_ws, size_t ws_size,
                              hipStream_t stream) {
  const float* x = (const float*)d_in[0];
  const int* edge_index = (const int*)d_in[1];
  const int* batch = (const int*)d_in[2];
  const int* src = edge_index;
  const int* dst = edge_index + N_EDGES;

  const float* wa[3] = {(const float*)d_in[3], (const float*)d_in[9],  (const float*)d_in[15]};
  const float* ba[3] = {(const float*)d_in[4], (const float*)d_in[10], (const float*)d_in[16]};
  const float* wb[3] = {(const float*)d_in[5], (const float*)d_in[11], (const float*)d_in[17]};
  const float* bb[3] = {(const float*)d_in[6], (const float*)d_in[12], (const float*)d_in[18]};
  const float* gg[3] = {(const float*)d_in[7], (const float*)d_in[13], (const float*)d_in[19]};
  const float* be[3] = {(const float*)d_in[8], (const float*)d_in[14], (const float*)d_in[20]};

  // -------- workspace layout --------
  // fp32 (zeroed): stats0(512) stats1(512) stats2(256) psums(8192) -> 9472 floats
  float* stats0 = (float*)d_ws;
  float* stats1 = stats0 + 512;
  float* stats2 = stats1 + 512;
  float* psums = stats2 + 256;
  // ints: bcnt(256, zeroed with floats) boff(NB+1 pad) bcur(256) row_ptr(N+1) deg(N) part(pad) adj(E)
  int* bcnt = (int*)(psums + (size_t)N_GRAPHS * 64);
  int* boff = bcnt + 256;
  int* bcur = boff + 256;
  int* row_ptr = bcur + 256;
  int* deg = row_ptr + (N_NODES + 1);
  int* part = deg + N_NODES;
  int* adj = part + ((PARTS + 3) & ~3);
  unsigned* pairs = (unsigned*)(adj + N_EDGES);
  // u16: b0, b1 (N*128 each), wfrag 6 x 16384
  unsigned short* b0 = (unsigned short*)(pairs + N_EDGES);
  unsigned short* b1 = b0 + (size_t)N_NODES * 128;
  unsigned short* wf0 = b1 + (size_t)N_NODES * 128;
  unsigned short* wf[6];
  for (int i = 0; i < 6; ++i) wf[i] = wf0 + (size_t)i * 16384;
  size_t needed = (size_t)((char*)(wf0 + 6 * 16384) - (char*)d_ws);
  if (ws_size < needed) return;

  // one memset covers stats+psums+bcnt (contiguous)
  hipMemsetAsync(stats0, 0, 9472 * 4 + 256 * 4, stream);

  // weight prep (single launch, 352 blocks)
  WPArgs wp;
  wp.w[0] = wa[0]; wp.w[1] = wb[0]; wp.w[2] = wa[1];
  wp.w[3] = wb[1]; wp.w[4] = wa[2]; wp.w[5] = wb[2];
  for (int i = 0; i < 6; ++i) wp.o[i] = wf[i];
  wprep_all_kernel<<<352, 256, 0, stream>>>(wp);

  // bucketed CSR build
  bcount_kernel<<<PSC_BLOCKS, 256, 0, stream>>>(dst, bcnt);
  bscan_kernel<<<1, 256, 0, stream>>>(bcnt, boff, bcur);
  pscatter_kernel<<<PSC_BLOCKS, 256, 0, stream>>>(src, dst, bcur, pairs);
  bdeg_kernel<<<NBUCKETS, 256, 0, stream>>>(pairs, boff, deg);
  partial_kernel<<<PARTS, 256, 0, stream>>>(deg, part);
  offset_scan_kernel<<<1, 512, 0, stream>>>(part, row_ptr);
  final_scan_kernel<<<PARTS, 256, 0, stream>>>(deg, part, row_ptr);
  bfill_kernel<<<NBUCKETS, 256, 0, stream>>>(pairs, boff, row_ptr, adj);

  const int gather_blocks = (N_NODES * 16 + 255) / 256;
  const int mlp_blocks = (N_NODES + 63) / 64;  // 1563

  // ---- layer 0 (gather reads fp32 x directly)
  gather_kernel<false, float><<<gather_blocks, 256, 0, stream>>>(x, nullptr, nullptr,
                                                                 row_ptr, adj, b0);
  mlp_mfma_kernel<128, true, false><<<mlp_blocks, 256, 0, stream>>>(b0, wf[0], ba[0], b1, nullptr, N_NODES);
  mlp_mfma_kernel<128, false, true><<<mlp_blocks, 256, 0, stream>>>(b1, wf[1], bb[0], b0, stats0, N_NODES);
  finalize_stats_kernel<128><<<1, 128, 0, stream>>>(stats0, gg[0], be[0]);

  // ---- layer 1
  gather_kernel<true, unsigned short><<<gather_blocks, 256, 0, stream>>>(
      b0, stats0 + 256, stats0 + 384, row_ptr, adj, b1);
  mlp_mfma_kernel<128, true, false><<<mlp_blocks, 256, 0, stream>>>(b1, wf[2], ba[1], b0, nullptr, N_NODES);
  mlp_mfma_kernel<128, false, true><<<mlp_blocks, 256, 0, stream>>>(b0, wf[3], bb[1], b1, stats1, N_NODES);
  finalize_stats_kernel<128><<<1, 128, 0, stream>>>(stats1, gg[1], be[1]);

  // ---- layer 2
  gather_kernel<true, unsigned short><<<gather_blocks, 256, 0, stream>>>(
      b1, stats1 + 256, stats1 + 384, row_ptr, adj, b0);
  mlp_mfma_kernel<128, true, false><<<mlp_blocks, 256, 0, stream>>>(b0, wf[4], ba[2], b1, nullptr, N_NODES);
  mlp_mfma_kernel<64, false, true><<<mlp_blocks, 256, 0, stream>>>(b1, wf[5], bb[2], b0, stats2, N_NODES);
  finalize_stats_kernel<64><<<1, 64, 0, stream>>>(stats2, gg[2], be[2]);

  // ---- pool (BN2+ReLU fused) + divide
  pool_seg_kernel<<<POOL_BLOCKS, 256, 0, stream>>>(b0, stats2 + 128, stats2 + 192, batch, psums);
  div_kernel<<<32, 256, 0, stream>>>(psums, batch, (float*)d_out);
}

// Round 6
// 712.387 us; speedup vs baseline: 12.9170x; 1.0345x over previous
//
#include <hip/hip_runtime.h>

// GIN encoder: 3 x [CSR gather-agg bf16, MFMA MLP(128->128->D) bf16, BN-stats] + segmented mean-pool
// N=100000 nodes, E=1600000 edges, G=128 graphs.
// R6: 4-deep software-pipelined gather (4 independent loads in flight per lane);
//     row_ptr produced directly by per-bucket histogram+scan (partial/offset/final
//     scans and deg[] deleted); bf16 buffers 16B-aligned.

#define N_NODES 100000
#define N_EDGES 1600000
#define N_GRAPHS 128
#define BN_EPS 1e-5f
#define POOL_CHUNK 400
#define POOL_BLOCKS ((N_NODES + POOL_CHUNK - 1) / POOL_CHUNK)  // 250
#define NBUCKETS ((N_NODES + 511) / 512)                       // 196
#define PSC_CHUNK 4096
#define PSC_BLOCKS ((N_EDGES + PSC_CHUNK - 1) / PSC_CHUNK)     // 391

typedef __attribute__((ext_vector_type(8))) short bf16x8;
typedef __attribute__((ext_vector_type(4))) float f32x4;

// ---------------------------------------------------------------- bf16 helpers
__device__ __forceinline__ unsigned short rne16(float f) {
  unsigned u = __float_as_uint(f);
  u += 0x7fffu + ((u >> 16) & 1u);
  return (unsigned short)(u >> 16);
}
__device__ __forceinline__ unsigned pack2(float lo, float hi) {
  unsigned a = __float_as_uint(lo); a += 0x7fffu + ((a >> 16) & 1u);
  unsigned b = __float_as_uint(hi); b += 0x7fffu + ((b >> 16) & 1u);
  return (a >> 16) | (b & 0xffff0000u);
}
__device__ __forceinline__ void bf2_to_f32(unsigned u, float& lo, float& hi) {
  lo = __uint_as_float(u << 16);
  hi = __uint_as_float(u & 0xffff0000u);
}
__device__ __forceinline__ void bf8_to_f32(uint4 u, float* f) {
  bf2_to_f32(u.x, f[0], f[1]);
  bf2_to_f32(u.y, f[2], f[3]);
  bf2_to_f32(u.z, f[4], f[5]);
  bf2_to_f32(u.w, f[6], f[7]);
}

// ---------------------------------------------------------------- weight prep (all 6 in one launch)
// W(K=128 x N fp32) -> frag-ordered bf16:
// flat = ((ntile*4 + kchunk)*64 + lane)*8 + j ; k = kchunk*32 + (lane>>4)*8 + j ; n = ntile*16 + (lane&15)
struct WPArgs {
  const float* w[6];
  unsigned short* o[6];
};
__global__ __launch_bounds__(256) void wprep_all_kernel(WPArgs wp) {
  int blk = blockIdx.x;
  int seg = (blk < 320) ? (blk >> 6) : 5;
  int base = (seg < 5) ? (seg << 6) : 320;
  int N = (seg == 5) ? 64 : 128;
  int f = (blk - base) * 256 + threadIdx.x;
  if (f >= 128 * N) return;
  int j = f & 7;
  int lane = (f >> 3) & 63;
  int t = f >> 9;
  int kchunk = t & 3, ntile = t >> 2;
  int k = kchunk * 32 + (lane >> 4) * 8 + j;
  int n = ntile * 16 + (lane & 15);
  wp.o[seg][f] = rne16(wp.w[seg][k * N + n]);
}

// ---------------------------------------------------------------- bucketed CSR build
// bucket = dst >> 9 (512 nodes per bucket)
__global__ __launch_bounds__(256) void bcount_kernel(const int* __restrict__ dst,
                                                     int* __restrict__ bcnt) {
  __shared__ int hist[NBUCKETS];
  int tid = threadIdx.x;
  for (int i = tid; i < NBUCKETS; i += 256) hist[i] = 0;
  __syncthreads();
  int e0 = blockIdx.x * PSC_CHUNK;
  int e1 = min(e0 + PSC_CHUNK, N_EDGES);
  for (int e = e0 + tid; e < e1; e += 256) atomicAdd(&hist[dst[e] >> 9], 1);
  __syncthreads();
  for (int i = tid; i < NBUCKETS; i += 256)
    if (hist[i]) atomicAdd(&bcnt[i], hist[i]);
}

__global__ __launch_bounds__(256) void bscan_kernel(const int* __restrict__ bcnt,
                                                    int* __restrict__ boff,
                                                    int* __restrict__ bcur,
                                                    int* __restrict__ row_ptr) {
  __shared__ int tmp[256];
  int tid = threadIdx.x;
  int c = (tid < NBUCKETS) ? bcnt[tid] : 0;
  tmp[tid] = c;
  __syncthreads();
  for (int off = 1; off < 256; off <<= 1) {
    int t = (tid >= off) ? tmp[tid - off] : 0;
    __syncthreads();
    tmp[tid] += t;
    __syncthreads();
  }
  if (tid < NBUCKETS) {
    int s = tmp[tid] - c;  // exclusive
    boff[tid] = s;
    bcur[tid] = s;
  }
  if (tid == 0) {
    boff[NBUCKETS] = N_EDGES;
    row_ptr[N_NODES] = N_EDGES;
  }
}

// block-aggregated pair scatter: pairs[pos] = (src<<9)|local_dst, grouped by bucket
__global__ __launch_bounds__(256) void pscatter_kernel(const int* __restrict__ src,
                                                       const int* __restrict__ dst,
                                                       int* __restrict__ bcur,
                                                       unsigned* __restrict__ pairs) {
  __shared__ int hist[NBUCKETS];
  __shared__ int base[NBUCKETS];
  int tid = threadIdx.x;
  for (int i = tid; i < NBUCKETS; i += 256) hist[i] = 0;
  __syncthreads();
  int e0 = blockIdx.x * PSC_CHUNK;
  int e1 = min(e0 + PSC_CHUNK, N_EDGES);
  for (int e = e0 + tid; e < e1; e += 256) atomicAdd(&hist[dst[e] >> 9], 1);
  __syncthreads();
  for (int i = tid; i < NBUCKETS; i += 256) {
    int c = hist[i];
    base[i] = c ? atomicAdd(&bcur[i], c) : 0;
    hist[i] = 0;  // becomes local cursor
  }
  __syncthreads();
  for (int e = e0 + tid; e < e1; e += 256) {
    int d = dst[e];
    int b = d >> 9;
    int slot = atomicAdd(&hist[b], 1);
    pairs[base[b] + slot] = ((unsigned)src[e] << 9) | (unsigned)(d & 511);
  }
}

// per-bucket degree histogram + block scan -> row_ptr written directly
// (bucket base offset in edge space == boff[b] since buckets are contiguous)
__global__ __launch_bounds__(256) void bdeg_scan_kernel(const unsigned* __restrict__ pairs,
                                                        const int* __restrict__ boff,
                                                        int* __restrict__ row_ptr) {
  __shared__ int h[512];
  __shared__ int tmp[256];
  int tid = threadIdx.x, b = blockIdx.x;
  h[tid] = 0;
  h[tid + 256] = 0;
  __syncthreads();
  int p0 = boff[b], p1 = boff[b + 1];
  for (int p = p0 + tid; p < p1; p += 256) atomicAdd(&h[pairs[p] & 511u], 1);
  __syncthreads();
  int a0 = h[2 * tid], a1 = h[2 * tid + 1];
  int s = a0 + a1;
  tmp[tid] = s;
  __syncthreads();
  for (int off = 1; off < 256; off <<= 1) {
    int t = (tid >= off) ? tmp[tid - off] : 0;
    __syncthreads();
    tmp[tid] += t;
    __syncthreads();
  }
  int excl = tmp[tid] - s;
  int base = p0;
  int n0 = b << 9;
  int i0 = 2 * tid, i1 = 2 * tid + 1;
  if (n0 + i0 < N_NODES) row_ptr[n0 + i0] = base + excl;
  if (n0 + i1 < N_NODES) row_ptr[n0 + i1] = base + excl + a0;
}

// per-bucket CSR fill: writes land in the bucket's contiguous adj region (L2-resident)
__global__ __launch_bounds__(256) void bfill_kernel(const unsigned* __restrict__ pairs,
                                                    const int* __restrict__ boff,
                                                    const int* __restrict__ row_ptr,
                                                    int* __restrict__ adj) {
  __shared__ int cur[512];
  int tid = threadIdx.x, b = blockIdx.x;
  int n0 = b << 9;
  for (int i = tid; i < 512; i += 256)
    cur[i] = (n0 + i < N_NODES) ? row_ptr[n0 + i] : 0;
  __syncthreads();
  int p0 = boff[b], p1 = boff[b + 1];
  for (int p = p0 + tid; p < p1; p += 256) {
    unsigned pr = pairs[p];
    int pos = atomicAdd(&cur[pr & 511u], 1);
    adj[pos] = (int)(pr >> 9);
  }
}

// ---------------------------------------------------------------- gather agg (fp32 or bf16 in, bf16 out)
// agg[n] = act(in[n]) + sum_{s in adj[n]} act(in[s]); 16 threads/node, 8 cols each.
// Neighbor loop unrolled x4: 4 independent row loads in flight per lane (latency hiding).
template <bool BN, typename TIN>
__global__ __launch_bounds__(256) void gather_kernel(
    const TIN* __restrict__ in, const float* __restrict__ scale,
    const float* __restrict__ shift, const int* __restrict__ row_ptr,
    const int* __restrict__ adj, unsigned short* __restrict__ agg) {
  int gid = blockIdx.x * 256 + threadIdx.x;
  int n = gid >> 4;
  if (n >= N_NODES) return;
  int c8 = gid & 15;
  float sc[8], sh[8];
  if (BN) {
    float4 s0 = ((const float4*)scale)[c8 * 2], s1 = ((const float4*)scale)[c8 * 2 + 1];
    float4 h0 = ((const float4*)shift)[c8 * 2], h1 = ((const float4*)shift)[c8 * 2 + 1];
    sc[0] = s0.x; sc[1] = s0.y; sc[2] = s0.z; sc[3] = s0.w;
    sc[4] = s1.x; sc[5] = s1.y; sc[6] = s1.z; sc[7] = s1.w;
    sh[0] = h0.x; sh[1] = h0.y; sh[2] = h0.z; sh[3] = h0.w;
    sh[4] = h1.x; sh[5] = h1.y; sh[6] = h1.z; sh[7] = h1.w;
  }
  float acc[8];
  auto addf = [&](const float* f) {
#pragma unroll
    for (int j = 0; j < 8; ++j)
      acc[j] += BN ? fmaxf(fmaf(f[j], sc[j], sh[j]), 0.f) : f[j];
  };
  int beg = row_ptr[n], end = row_ptr[n + 1];
  // self term
  {
    float f[8];
    if constexpr (sizeof(TIN) == 2) {
      uint4 u = ((const uint4*)((const unsigned short*)in + (size_t)n * 128))[c8];
      bf8_to_f32(u, f);
    } else {
      const float4* p = (const float4*)((const float*)in + (size_t)n * 128) + c8 * 2;
      float4 a = p[0], b = p[1];
      f[0] = a.x; f[1] = a.y; f[2] = a.z; f[3] = a.w;
      f[4] = b.x; f[5] = b.y; f[6] = b.z; f[7] = b.w;
    }
#pragma unroll
    for (int j = 0; j < 8; ++j)
      acc[j] = BN ? fmaxf(fmaf(f[j], sc[j], sh[j]), 0.f) : f[j];
  }
  int k = beg;
  if constexpr (sizeof(TIN) == 2) {
    const unsigned short* inb = (const unsigned short*)in;
    for (; k + 4 <= end; k += 4) {
      int s0 = adj[k], s1 = adj[k + 1], s2 = adj[k + 2], s3 = adj[k + 3];
      uint4 u0 = ((const uint4*)(inb + (size_t)s0 * 128))[c8];
      uint4 u1 = ((const uint4*)(inb + (size_t)s1 * 128))[c8];
      uint4 u2 = ((const uint4*)(inb + (size_t)s2 * 128))[c8];
      uint4 u3 = ((const uint4*)(inb + (size_t)s3 * 128))[c8];
      float f[8];
      bf8_to_f32(u0, f); addf(f);
      bf8_to_f32(u1, f); addf(f);
      bf8_to_f32(u2, f); addf(f);
      bf8_to_f32(u3, f); addf(f);
    }
    for (; k < end; ++k) {
      uint4 u = ((const uint4*)(inb + (size_t)adj[k] * 128))[c8];
      float f[8];
      bf8_to_f32(u, f);
      addf(f);
    }
  } else {
    const float* inf = (const float*)in;
    for (; k + 4 <= end; k += 4) {
      int s0 = adj[k], s1 = adj[k + 1], s2 = adj[k + 2], s3 = adj[k + 3];
      const float4* p0 = (const float4*)(inf + (size_t)s0 * 128) + c8 * 2;
      const float4* p1 = (const float4*)(inf + (size_t)s1 * 128) + c8 * 2;
      const float4* p2 = (const float4*)(inf + (size_t)s2 * 128) + c8 * 2;
      const float4* p3 = (const float4*)(inf + (size_t)s3 * 128) + c8 * 2;
      float4 a0 = p0[0], b0 = p0[1], a1 = p1[0], b1 = p1[1];
      float4 a2 = p2[0], b2 = p2[1], a3 = p3[0], b3 = p3[1];
      float f[8];
#define ACC8(A, B) \
      f[0] = A.x; f[1] = A.y; f[2] = A.z; f[3] = A.w; \
      f[4] = B.x; f[5] = B.y; f[6] = B.z; f[7] = B.w; \
      addf(f);
      ACC8(a0, b0) ACC8(a1, b1) ACC8(a2, b2) ACC8(a3, b3)
#undef ACC8
    }
    for (; k < end; ++k) {
      const float4* p = (const float4*)(inf + (size_t)adj[k] * 128) + c8 * 2;
      float4 a = p[0], b = p[1];
      float f[8];
      f[0] = a.x; f[1] = a.y; f[2] = a.z; f[3] = a.w;
      f[4] = b.x; f[5] = b.y; f[6] = b.z; f[7] = b.w;
      addf(f);
    }
  }
  uint4 o;
  o.x = pack2(acc[0], acc[1]); o.y = pack2(acc[2], acc[3]);
  o.z = pack2(acc[4], acc[5]); o.w = pack2(acc[6], acc[7]);
  ((uint4*)(agg + (size_t)n * 128))[c8] = o;
}

// ---------------------------------------------------------------- MFMA MLP: O = [relu](A @ W + b), bf16 in/out
template <int N, bool RELU, bool STATS>
__global__ __launch_bounds__(256) void mlp_mfma_kernel(
    const unsigned short* __restrict__ A, const unsigned short* __restrict__ Wf,
    const float* __restrict__ bias, unsigned short* __restrict__ O,
    float* __restrict__ gstats, int M) {
  constexpr int NT = N / 16;
  __shared__ unsigned short sW[128 * N];
  __shared__ float sSt[STATS ? 2 * N : 1];

  {
    const uint4* s = (const uint4*)Wf;
    uint4* d = (uint4*)sW;
    for (int i = threadIdx.x; i < 128 * N / 8; i += 256) d[i] = s[i];
  }
  __syncthreads();

  int lane = threadIdx.x & 63;
  int wave = threadIdx.x >> 6;
  int m = lane & 15, quad = lane >> 4;
  int row0w = blockIdx.x * 64 + wave * 16;
  int row = row0w + m;

  bf16x8 a[4];
  if (row < M) {
    const bf16x8* Ar = (const bf16x8*)(A + (size_t)row * 128);
#pragma unroll
    for (int kc = 0; kc < 4; ++kc) a[kc] = Ar[kc * 4 + quad];
  } else {
#pragma unroll
    for (int kc = 0; kc < 4; ++kc)
#pragma unroll
      for (int j = 0; j < 8; ++j) a[kc][j] = 0;
  }

  f32x4 acc[NT];
#pragma unroll
  for (int nt = 0; nt < NT; ++nt) {
    float bv = bias[nt * 16 + m];
#pragma unroll
    for (int r = 0; r < 4; ++r) acc[nt][r] = bv;
  }

  const bf16x8* sW8 = (const bf16x8*)sW;
#pragma unroll
  for (int kc = 0; kc < 4; ++kc) {
#pragma unroll
    for (int nt = 0; nt < NT; ++nt)
      acc[nt] = __builtin_amdgcn_mfma_f32_16x16x32_bf16(a[kc], sW8[(nt * 4 + kc) * 64 + lane],
                                                        acc[nt], 0, 0, 0);
  }

#pragma unroll
  for (int nt = 0; nt < NT; ++nt) {
#pragma unroll
    for (int r = 0; r < 4; ++r) {
      int grow = row0w + quad * 4 + r;
      if (grow < M) {
        float v = acc[nt][r];
        if (RELU) v = fmaxf(v, 0.f);
        O[(size_t)grow * N + nt * 16 + m] = rne16(v);
      }
    }
  }

  if (STATS) {
    for (int i = threadIdx.x; i < 2 * N; i += 256) sSt[i] = 0.f;
    __syncthreads();
#pragma unroll
    for (int nt = 0; nt < NT; ++nt) {
      float s = 0.f, ss = 0.f;
#pragma unroll
      for (int r = 0; r < 4; ++r) {
        if (row0w + quad * 4 + r < M) {
          float v = acc[nt][r];
          s += v;
          ss += v * v;
        }
      }
      atomicAdd(&sSt[nt * 16 + m], s);
      atomicAdd(&sSt[N + nt * 16 + m], ss);
    }
    __syncthreads();
    for (int i = threadIdx.x; i < 2 * N; i += 256) atomicAdd(&gstats[i], sSt[i]);
  }
}

// ---------------------------------------------------------------- BN finalize: stats -> scale/shift
template <int DOUT>
__global__ void finalize_stats_kernel(float* __restrict__ stats, const float* __restrict__ g,
                                      const float* __restrict__ be) {
  int c = threadIdx.x;
  if (c < DOUT) {
    float inv_n = 1.0f / (float)N_NODES;
    float mean = stats[c] * inv_n;
    float var = stats[DOUT + c] * inv_n - mean * mean;
    float sc = g[c] * rsqrtf(var + BN_EPS);
    stats[2 * DOUT + c] = sc;
    stats[3 * DOUT + c] = be[c] - mean * sc;
  }
}

// ---------------------------------------------------------------- segmented mean pool (bf16 in, BN+ReLU fused)
__global__ __launch_bounds__(256) void pool_seg_kernel(
    const unsigned short* __restrict__ h, const float* __restrict__ scale,
    const float* __restrict__ shift, const int* __restrict__ batch,
    float* __restrict__ sums) {
  __shared__ float sacc[N_GRAPHS * 64];
  int tid = threadIdx.x;
  for (int i = tid; i < N_GRAPHS * 64; i += 256) sacc[i] = 0.f;

  int base = blockIdx.x * POOL_CHUNK;
  int last = min(base + POOL_CHUNK, N_NODES) - 1;
  int c4 = tid & 15;
  int r = tid >> 4;
  float4 sc = ((const float4*)scale)[c4];
  float4 sh = ((const float4*)shift)[c4];
  __syncthreads();

  float4 acc = make_float4(0.f, 0.f, 0.f, 0.f);
  int gcur = -1;
#pragma unroll 1
  for (int j = 0; j < POOL_CHUNK / 16; ++j) {
    int node = base + j * 16 + r;
    if (node >= N_NODES) break;
    int g = batch[node];
    if (g != gcur) {
      if (gcur >= 0) {
        float* p = &sacc[gcur * 64 + c4 * 4];
        atomicAdd(p + 0, acc.x); atomicAdd(p + 1, acc.y);
        atomicAdd(p + 2, acc.z); atomicAdd(p + 3, acc.w);
      }
      gcur = g;
      acc = make_float4(0.f, 0.f, 0.f, 0.f);
    }
    uint2 u = ((const uint2*)(h + (size_t)node * 64))[c4];
    float f0, f1, f2, f3;
    bf2_to_f32(u.x, f0, f1);
    bf2_to_f32(u.y, f2, f3);
    acc.x += fmaxf(fmaf(f0, sc.x, sh.x), 0.f);
    acc.y += fmaxf(fmaf(f1, sc.y, sh.y), 0.f);
    acc.z += fmaxf(fmaf(f2, sc.z, sh.z), 0.f);
    acc.w += fmaxf(fmaf(f3, sc.w, sh.w), 0.f);
  }
  if (gcur >= 0) {
    float* p = &sacc[gcur * 64 + c4 * 4];
    atomicAdd(p + 0, acc.x); atomicAdd(p + 1, acc.y);
    atomicAdd(p + 2, acc.z); atomicAdd(p + 3, acc.w);
  }
  __syncthreads();

  int gmin = batch[base];
  int gmax = batch[last];
  for (int g = gmin; g <= gmax; ++g)
    for (int i = tid; i < 64; i += 256)
      atomicAdd(&sums[g * 64 + i], sacc[g * 64 + i]);
}

// ---------------------------------------------------------------- divide by counts (binary search)
__global__ __launch_bounds__(256) void div_kernel(const float* __restrict__ sums,
                                                  const int* __restrict__ batch,
                                                  float* __restrict__ out) {
  int i = blockIdx.x * blockDim.x + threadIdx.x;
  if (i >= N_GRAPHS * 64) return;
  int g = i >> 6;
  int lo = 0, hi = N_NODES;
  while (lo < hi) { int m = (lo + hi) >> 1; if (batch[m] < g) lo = m + 1; else hi = m; }
  int lb = lo;
  lo = 0; hi = N_NODES;
  while (lo < hi) { int m = (lo + hi) >> 1; if (batch[m] <= g) lo = m + 1; else hi = m; }
  float cnt = (float)(lo - lb);
  out[i] = sums[i] / fmaxf(cnt, 1.0f);
}

// ---------------------------------------------------------------- launch
extern "C" void kernel_launch(void* const* d_in, const int* in_sizes, int n_in,
                              void* d_out, int out_size, void* d_ws, size_t ws_size,
                              hipStream_t stream) {
  const float* x = (const float*)d_in[0];
  const int* edge_index = (const int*)d_in[1];
  const int* batch = (const int*)d_in[2];
  const int* src = edge_index;
  const int* dst = edge_index + N_EDGES;

  const float* wa[3] = {(const float*)d_in[3], (const float*)d_in[9],  (const float*)d_in[15]};
  const float* ba[3] = {(const float*)d_in[4], (const float*)d_in[10], (const float*)d_in[16]};
  const float* wb[3] = {(const float*)d_in[5], (const float*)d_in[11], (const float*)d_in[17]};
  const float* bb[3] = {(const float*)d_in[6], (const float*)d_in[12], (const float*)d_in[18]};
  const float* gg[3] = {(const float*)d_in[7], (const float*)d_in[13], (const float*)d_in[19]};
  const float* be[3] = {(const float*)d_in[8], (const float*)d_in[14], (const float*)d_in[20]};

  // -------- workspace layout --------
  // fp32 (zeroed): stats0(512) stats1(512) stats2(256) psums(8192) -> 9472 floats (37888 B, 16B-aligned)
  float* stats0 = (float*)d_ws;
  float* stats1 = stats0 + 512;
  float* stats2 = stats1 + 512;
  float* psums = stats2 + 256;
  // ints: bcnt(256, zeroed with floats) boff(256) bcur(256) row_ptr(100004 pad) adj(E) pairs(E)
  int* bcnt = (int*)(psums + (size_t)N_GRAPHS * 64);
  int* boff = bcnt + 256;
  int* bcur = boff + 256;
  int* row_ptr = bcur + 256;
  int* adj = row_ptr + 100004;  // N+1 rounded up to x4 -> keeps 16B alignment downstream
  unsigned* pairs = (unsigned*)(adj + N_EDGES);
  // u16 (16B-aligned): b0, b1 (N*128 each), wfrag 6 x 16384
  unsigned short* b0 = (unsigned short*)(pairs + N_EDGES);
  unsigned short* b1 = b0 + (size_t)N_NODES * 128;
  unsigned short* wf0 = b1 + (size_t)N_NODES * 128;
  unsigned short* wf[6];
  for (int i = 0; i < 6; ++i) wf[i] = wf0 + (size_t)i * 16384;
  size_t needed = (size_t)((char*)(wf0 + 6 * 16384) - (char*)d_ws);
  if (ws_size < needed) return;

  // one memset covers stats+psums+bcnt (contiguous)
  hipMemsetAsync(stats0, 0, 9472 * 4 + 256 * 4, stream);

  // weight prep (single launch, 352 blocks)
  WPArgs wp;
  wp.w[0] = wa[0]; wp.w[1] = wb[0]; wp.w[2] = wa[1];
  wp.w[3] = wb[1]; wp.w[4] = wa[2]; wp.w[5] = wb[2];
  for (int i = 0; i < 6; ++i) wp.o[i] = wf[i];
  wprep_all_kernel<<<352, 256, 0, stream>>>(wp);

  // bucketed CSR build (row_ptr comes straight from bucket histograms)
  bcount_kernel<<<PSC_BLOCKS, 256, 0, stream>>>(dst, bcnt);
  bscan_kernel<<<1, 256, 0, stream>>>(bcnt, boff, bcur, row_ptr);
  pscatter_kernel<<<PSC_BLOCKS, 256, 0, stream>>>(src, dst, bcur, pairs);
  bdeg_scan_kernel<<<NBUCKETS, 256, 0, stream>>>(pairs, boff, row_ptr);
  bfill_kernel<<<NBUCKETS, 256, 0, stream>>>(pairs, boff, row_ptr, adj);

  const int gather_blocks = (N_NODES * 16 + 255) / 256;
  const int mlp_blocks = (N_NODES + 63) / 64;  // 1563

  // ---- layer 0 (gather reads fp32 x directly)
  gather_kernel<false, float><<<gather_blocks, 256, 0, stream>>>(x, nullptr, nullptr,
                                                                 row_ptr, adj, b0);
  mlp_mfma_kernel<128, true, false><<<mlp_blocks, 256, 0, stream>>>(b0, wf[0], ba[0], b1, nullptr, N_NODES);
  mlp_mfma_kernel<128, false, true><<<mlp_blocks, 256, 0, stream>>>(b1, wf[1], bb[0], b0, stats0, N_NODES);
  finalize_stats_kernel<128><<<1, 128, 0, stream>>>(stats0, gg[0], be[0]);

  // ---- layer 1
  gather_kernel<true, unsigned short><<<gather_blocks, 256, 0, stream>>>(
      b0, stats0 + 256, stats0 + 384, row_ptr, adj, b1);
  mlp_mfma_kernel<128, true, false><<<mlp_blocks, 256, 0, stream>>>(b1, wf[2], ba[1], b0, nullptr, N_NODES);
  mlp_mfma_kernel<128, false, true><<<mlp_blocks, 256, 0, stream>>>(b0, wf[3], bb[1], b1, stats1, N_NODES);
  finalize_stats_kernel<128><<<1, 128, 0, stream>>>(stats1, gg[1], be[1]);

  // ---- layer 2
  gather_kernel<true, unsigned short><<<gather_blocks, 256, 0, stream>>>(
      b1, stats1 + 256, stats1 + 384, row_ptr, adj, b0);
  mlp_mfma_kernel<128, true, false><<<mlp_blocks, 256, 0, stream>>>(b0, wf[4], ba[2], b1, nullptr, N_NODES);
  mlp_mfma_kernel<64, false, true><<<mlp_blocks, 256, 0, stream>>>(b1, wf[5], bb[2], b0, stats2, N_NODES);
  finalize_stats_kernel<64><<<1, 64, 0, stream>>>(stats2, gg[2], be[2]);

  // ---- pool (BN2+ReLU fused) + divide
  pool_seg_kernel<<<POOL_BLOCKS, 256, 0, stream>>>(b0, stats2 + 128, stats2 + 192, batch, psums);
  div_kernel<<<32, 256, 0, stream>>>(psums, batch, (float*)d_out);
}

// Round 7
// 660.552 us; speedup vs baseline: 13.9306x; 1.0785x over previous
//
#include <hip/hip_runtime.h>

// GIN encoder: 3 x [CSR gather-agg bf16, fused MFMA MLP(128->128->D), BN-stats] + segmented mean-pool
// N=100000 nodes, E=1600000 edges, G=128 graphs.
// R7: MLP1+MLP2 fused per layer (H1 relayout via per-wave XOR-swizzled LDS bounce,
//     no mid buffer, Wa staged once per grid-stride block, Wb frags from L2);
//     gather kernels split by name for profiler observability.

#define N_NODES 100000
#define N_EDGES 1600000
#define N_GRAPHS 128
#define BN_EPS 1e-5f
#define POOL_CHUNK 400
#define POOL_BLOCKS ((N_NODES + POOL_CHUNK - 1) / POOL_CHUNK)  // 250
#define NBUCKETS ((N_NODES + 511) / 512)                       // 196
#define PSC_CHUNK 4096
#define PSC_BLOCKS ((N_EDGES + PSC_CHUNK - 1) / PSC_CHUNK)     // 391
#define MLP_TILES ((N_NODES + 63) / 64)                        // 1563

typedef __attribute__((ext_vector_type(8))) short bf16x8;
typedef __attribute__((ext_vector_type(4))) float f32x4;

// ---------------------------------------------------------------- bf16 helpers
__device__ __forceinline__ unsigned short rne16(float f) {
  unsigned u = __float_as_uint(f);
  u += 0x7fffu + ((u >> 16) & 1u);
  return (unsigned short)(u >> 16);
}
__device__ __forceinline__ unsigned pack2(float lo, float hi) {
  unsigned a = __float_as_uint(lo); a += 0x7fffu + ((a >> 16) & 1u);
  unsigned b = __float_as_uint(hi); b += 0x7fffu + ((b >> 16) & 1u);
  return (a >> 16) | (b & 0xffff0000u);
}
__device__ __forceinline__ void bf2_to_f32(unsigned u, float& lo, float& hi) {
  lo = __uint_as_float(u << 16);
  hi = __uint_as_float(u & 0xffff0000u);
}
__device__ __forceinline__ void bf8_to_f32(uint4 u, float* f) {
  bf2_to_f32(u.x, f[0], f[1]);
  bf2_to_f32(u.y, f[2], f[3]);
  bf2_to_f32(u.z, f[4], f[5]);
  bf2_to_f32(u.w, f[6], f[7]);
}

// ---------------------------------------------------------------- weight prep (all 6 in one launch)
// W(K=128 x N fp32) -> B-operand frag-ordered bf16:
// flat = ((ntile*4 + kchunk)*64 + lane)*8 + j ; k = kchunk*32 + (lane>>4)*8 + j ; n = ntile*16 + (lane&15)
struct WPArgs {
  const float* w[6];
  unsigned short* o[6];
};
__global__ __launch_bounds__(256) void wprep_all_kernel(WPArgs wp) {
  int blk = blockIdx.x;
  int seg = (blk < 320) ? (blk >> 6) : 5;
  int base = (seg < 5) ? (seg << 6) : 320;
  int N = (seg == 5) ? 64 : 128;
  int f = (blk - base) * 256 + threadIdx.x;
  if (f >= 128 * N) return;
  int j = f & 7;
  int lane = (f >> 3) & 63;
  int t = f >> 9;
  int kchunk = t & 3, ntile = t >> 2;
  int k = kchunk * 32 + (lane >> 4) * 8 + j;
  int n = ntile * 16 + (lane & 15);
  wp.o[seg][f] = rne16(wp.w[seg][k * N + n]);
}

// ---------------------------------------------------------------- bucketed CSR build
__global__ __launch_bounds__(256) void bcount_kernel(const int* __restrict__ dst,
                                                     int* __restrict__ bcnt) {
  __shared__ int hist[NBUCKETS];
  int tid = threadIdx.x;
  for (int i = tid; i < NBUCKETS; i += 256) hist[i] = 0;
  __syncthreads();
  int e0 = blockIdx.x * PSC_CHUNK;
  int e1 = min(e0 + PSC_CHUNK, N_EDGES);
  for (int e = e0 + tid; e < e1; e += 256) atomicAdd(&hist[dst[e] >> 9], 1);
  __syncthreads();
  for (int i = tid; i < NBUCKETS; i += 256)
    if (hist[i]) atomicAdd(&bcnt[i], hist[i]);
}

__global__ __launch_bounds__(256) void bscan_kernel(const int* __restrict__ bcnt,
                                                    int* __restrict__ boff,
                                                    int* __restrict__ bcur,
                                                    int* __restrict__ row_ptr) {
  __shared__ int tmp[256];
  int tid = threadIdx.x;
  int c = (tid < NBUCKETS) ? bcnt[tid] : 0;
  tmp[tid] = c;
  __syncthreads();
  for (int off = 1; off < 256; off <<= 1) {
    int t = (tid >= off) ? tmp[tid - off] : 0;
    __syncthreads();
    tmp[tid] += t;
    __syncthreads();
  }
  if (tid < NBUCKETS) {
    int s = tmp[tid] - c;
    boff[tid] = s;
    bcur[tid] = s;
  }
  if (tid == 0) {
    boff[NBUCKETS] = N_EDGES;
    row_ptr[N_NODES] = N_EDGES;
  }
}

__global__ __launch_bounds__(256) void pscatter_kernel(const int* __restrict__ src,
                                                       const int* __restrict__ dst,
                                                       int* __restrict__ bcur,
                                                       unsigned* __restrict__ pairs) {
  __shared__ int hist[NBUCKETS];
  __shared__ int base[NBUCKETS];
  int tid = threadIdx.x;
  for (int i = tid; i < NBUCKETS; i += 256) hist[i] = 0;
  __syncthreads();
  int e0 = blockIdx.x * PSC_CHUNK;
  int e1 = min(e0 + PSC_CHUNK, N_EDGES);
  for (int e = e0 + tid; e < e1; e += 256) atomicAdd(&hist[dst[e] >> 9], 1);
  __syncthreads();
  for (int i = tid; i < NBUCKETS; i += 256) {
    int c = hist[i];
    base[i] = c ? atomicAdd(&bcur[i], c) : 0;
    hist[i] = 0;
  }
  __syncthreads();
  for (int e = e0 + tid; e < e1; e += 256) {
    int d = dst[e];
    int b = d >> 9;
    int slot = atomicAdd(&hist[b], 1);
    pairs[base[b] + slot] = ((unsigned)src[e] << 9) | (unsigned)(d & 511);
  }
}

__global__ __launch_bounds__(256) void bdeg_scan_kernel(const unsigned* __restrict__ pairs,
                                                        const int* __restrict__ boff,
                                                        int* __restrict__ row_ptr) {
  __shared__ int h[512];
  __shared__ int tmp[256];
  int tid = threadIdx.x, b = blockIdx.x;
  h[tid] = 0;
  h[tid + 256] = 0;
  __syncthreads();
  int p0 = boff[b], p1 = boff[b + 1];
  for (int p = p0 + tid; p < p1; p += 256) atomicAdd(&h[pairs[p] & 511u], 1);
  __syncthreads();
  int a0 = h[2 * tid], a1 = h[2 * tid + 1];
  int s = a0 + a1;
  tmp[tid] = s;
  __syncthreads();
  for (int off = 1; off < 256; off <<= 1) {
    int t = (tid >= off) ? tmp[tid - off] : 0;
    __syncthreads();
    tmp[tid] += t;
    __syncthreads();
  }
  int excl = tmp[tid] - s;
  int n0 = b << 9;
  int i0 = 2 * tid, i1 = 2 * tid + 1;
  if (n0 + i0 < N_NODES) row_ptr[n0 + i0] = p0 + excl;
  if (n0 + i1 < N_NODES) row_ptr[n0 + i1] = p0 + excl + a0;
}

__global__ __launch_bounds__(256) void bfill_kernel(const unsigned* __restrict__ pairs,
                                                    const int* __restrict__ boff,
                                                    const int* __restrict__ row_ptr,
                                                    int* __restrict__ adj) {
  __shared__ int cur[512];
  int tid = threadIdx.x, b = blockIdx.x;
  int n0 = b << 9;
  for (int i = tid; i < 512; i += 256)
    cur[i] = (n0 + i < N_NODES) ? row_ptr[n0 + i] : 0;
  __syncthreads();
  int p0 = boff[b], p1 = boff[b + 1];
  for (int p = p0 + tid; p < p1; p += 256) {
    unsigned pr = pairs[p];
    int pos = atomicAdd(&cur[pr & 511u], 1);
    adj[pos] = (int)(pr >> 9);
  }
}

// ---------------------------------------------------------------- gather agg, layer 0 (fp32 in, bf16 out)
__global__ __launch_bounds__(256) void gather_l0_kernel(
    const float* __restrict__ in, const int* __restrict__ row_ptr,
    const int* __restrict__ adj, unsigned short* __restrict__ agg) {
  int gid = blockIdx.x * 256 + threadIdx.x;
  int n = gid >> 4;
  if (n >= N_NODES) return;
  int c8 = gid & 15;
  float acc[8];
  {
    const float4* p = (const float4*)(in + (size_t)n * 128) + c8 * 2;
    float4 a = p[0], b = p[1];
    acc[0] = a.x; acc[1] = a.y; acc[2] = a.z; acc[3] = a.w;
    acc[4] = b.x; acc[5] = b.y; acc[6] = b.z; acc[7] = b.w;
  }
  int beg = row_ptr[n], end = row_ptr[n + 1];
  for (int k = beg; k < end; ++k) {
    const float4* p = (const float4*)(in + (size_t)adj[k] * 128) + c8 * 2;
    float4 a = p[0], b = p[1];
    acc[0] += a.x; acc[1] += a.y; acc[2] += a.z; acc[3] += a.w;
    acc[4] += b.x; acc[5] += b.y; acc[6] += b.z; acc[7] += b.w;
  }
  uint4 o;
  o.x = pack2(acc[0], acc[1]); o.y = pack2(acc[2], acc[3]);
  o.z = pack2(acc[4], acc[5]); o.w = pack2(acc[6], acc[7]);
  ((uint4*)(agg + (size_t)n * 128))[c8] = o;
}

// ---------------------------------------------------------------- gather agg, layers 1/2 (bf16 in/out, BN+ReLU fused)
__global__ __launch_bounds__(256) void gather_ln_kernel(
    const unsigned short* __restrict__ in, const float* __restrict__ scale,
    const float* __restrict__ shift, const int* __restrict__ row_ptr,
    const int* __restrict__ adj, unsigned short* __restrict__ agg) {
  int gid = blockIdx.x * 256 + threadIdx.x;
  int n = gid >> 4;
  if (n >= N_NODES) return;
  int c8 = gid & 15;
  float sc[8], sh[8];
  {
    float4 s0 = ((const float4*)scale)[c8 * 2], s1 = ((const float4*)scale)[c8 * 2 + 1];
    float4 h0 = ((const float4*)shift)[c8 * 2], h1 = ((const float4*)shift)[c8 * 2 + 1];
    sc[0] = s0.x; sc[1] = s0.y; sc[2] = s0.z; sc[3] = s0.w;
    sc[4] = s1.x; sc[5] = s1.y; sc[6] = s1.z; sc[7] = s1.w;
    sh[0] = h0.x; sh[1] = h0.y; sh[2] = h0.z; sh[3] = h0.w;
    sh[4] = h1.x; sh[5] = h1.y; sh[6] = h1.z; sh[7] = h1.w;
  }
  float acc[8];
  auto addf = [&](const float* f) {
#pragma unroll
    for (int j = 0; j < 8; ++j) acc[j] += fmaxf(fmaf(f[j], sc[j], sh[j]), 0.f);
  };
  int beg = row_ptr[n], end = row_ptr[n + 1];
  {
    uint4 u = ((const uint4*)(in + (size_t)n * 128))[c8];
    float f[8];
    bf8_to_f32(u, f);
#pragma unroll
    for (int j = 0; j < 8; ++j) acc[j] = fmaxf(fmaf(f[j], sc[j], sh[j]), 0.f);
  }
  int k = beg;
  for (; k + 4 <= end; k += 4) {
    int s0 = adj[k], s1 = adj[k + 1], s2 = adj[k + 2], s3 = adj[k + 3];
    uint4 u0 = ((const uint4*)(in + (size_t)s0 * 128))[c8];
    uint4 u1 = ((const uint4*)(in + (size_t)s1 * 128))[c8];
    uint4 u2 = ((const uint4*)(in + (size_t)s2 * 128))[c8];
    uint4 u3 = ((const uint4*)(in + (size_t)s3 * 128))[c8];
    float f[8];
    bf8_to_f32(u0, f); addf(f);
    bf8_to_f32(u1, f); addf(f);
    bf8_to_f32(u2, f); addf(f);
    bf8_to_f32(u3, f); addf(f);
  }
  for (; k < end; ++k) {
    uint4 u = ((const uint4*)(in + (size_t)adj[k] * 128))[c8];
    float f[8];
    bf8_to_f32(u, f);
    addf(f);
  }
  uint4 o;
  o.x = pack2(acc[0], acc[1]); o.y = pack2(acc[2], acc[3]);
  o.z = pack2(acc[4], acc[5]); o.w = pack2(acc[6], acc[7]);
  ((uint4*)(agg + (size_t)n * 128))[c8] = o;
}

// ---------------------------------------------------------------- fused MLP: O = mlp2(relu(mlp1(A)))
// A: M x 128 bf16. Wfa/Wfb: B-operand frag-ordered bf16 (wprep layout).
// GEMM1: mfma(x_frag, wa_frag) -> H1[m=quad*4+r][n1=lane&15+16*n1t]
//   (verified convention: A-operand's lane&15 index -> D row quad*4+r; B's -> D col lane&15)
// H1 bounce: per-wave XOR-swizzled LDS (16B chunk c stored at c^row), in-order DS, no barrier.
// GEMM2: mfma(h1_frag, wb_frag) -> H2[m=quad*4+r][n2=lane&15+16*n2t]; bias init in acc.
// Column stats (sum/sumsq) accumulated to LDS then one global atomic pass per block.
template <int N2>
__global__ __launch_bounds__(256) void fused_mlp_kernel(
    const unsigned short* __restrict__ A, const unsigned short* __restrict__ Wfa,
    const unsigned short* __restrict__ Wfb, const float* __restrict__ ba,
    const float* __restrict__ bb, unsigned short* __restrict__ O,
    float* __restrict__ gstats, int M, int ntiles) {
  constexpr int NT2 = N2 / 16;
  __shared__ unsigned short sWa[128 * 128];    // 32 KB, frag-ordered
  __shared__ unsigned short sH1[4][16 * 128];  // 16 KB, per-wave bounce
  __shared__ float sB[256];                    // ba(128) | bb(<=128)
  __shared__ float sSt[2 * N2];

  int tid = threadIdx.x;
  {
    const uint4* s = (const uint4*)Wfa;
    uint4* d = (uint4*)sWa;
    for (int i = tid; i < 128 * 128 / 8; i += 256) d[i] = s[i];
  }
  if (tid < 128) sB[tid] = ba[tid];
  else if (tid - 128 < N2) sB[tid] = bb[tid - 128];
  for (int i = tid; i < 2 * N2; i += 256) sSt[i] = 0.f;
  __syncthreads();

  int lane = tid & 63, wave = tid >> 6;
  int m16 = lane & 15, quad = lane >> 4;
  unsigned short* h1 = &sH1[wave][0];
  const bf16x8* sWa8 = (const bf16x8*)sWa;
  const bf16x8* Wfb8 = (const bf16x8*)Wfb;

  for (int t = blockIdx.x; t < ntiles; t += gridDim.x) {
    int row0 = t * 64 + wave * 16;
    int row = row0 + m16;

    bf16x8 a[4];
    if (row < M) {
      const bf16x8* Ar = (const bf16x8*)(A + (size_t)row * 128);
#pragma unroll
      for (int kc = 0; kc < 4; ++kc) a[kc] = Ar[kc * 4 + quad];
    } else {
#pragma unroll
      for (int kc = 0; kc < 4; ++kc)
#pragma unroll
        for (int j = 0; j < 8; ++j) a[kc][j] = 0;
    }

    f32x4 acc2[NT2];
#pragma unroll
    for (int nt = 0; nt < NT2; ++nt) {
      float bv = sB[128 + nt * 16 + m16];
#pragma unroll
      for (int r = 0; r < 4; ++r) acc2[nt][r] = bv;
    }

#pragma unroll
    for (int kc2 = 0; kc2 < 4; ++kc2) {
      // prefetch Wb frags for this kc2 (L2-hot, lands during GEMM1+bounce)
      bf16x8 wb[NT2];
#pragma unroll
      for (int nt = 0; nt < NT2; ++nt) wb[nt] = Wfb8[(nt * 4 + kc2) * 64 + lane];

      // GEMM1 for n1 tiles {2*kc2, 2*kc2+1}
#pragma unroll
      for (int t2 = 0; t2 < 2; ++t2) {
        int n1t = 2 * kc2 + t2;
        float bv = sB[n1t * 16 + m16];
        f32x4 acc1 = {bv, bv, bv, bv};
#pragma unroll
        for (int kc = 0; kc < 4; ++kc)
          acc1 = __builtin_amdgcn_mfma_f32_16x16x32_bf16(
              a[kc], sWa8[(n1t * 4 + kc) * 64 + lane], acc1, 0, 0, 0);
        int n1 = n1t * 16 + m16;
        int c = n1 >> 3;
#pragma unroll
        for (int r = 0; r < 4; ++r) {
          int mrow = quad * 4 + r;
          h1[mrow * 128 + (((c ^ mrow) & 15) << 3) + (n1 & 7)] =
              rne16(fmaxf(acc1[r], 0.f));
        }
      }
      // read back H1[m=m16][k=kc2*32+quad*8 .. +7] (same-wave in-order DS)
      int cR = kc2 * 4 + quad;
      bf16x8 hf = *(const bf16x8*)&h1[m16 * 128 + (((cR ^ m16) & 15) << 3)];
#pragma unroll
      for (int nt = 0; nt < NT2; ++nt)
        acc2[nt] = __builtin_amdgcn_mfma_f32_16x16x32_bf16(hf, wb[nt], acc2[nt], 0, 0, 0);
    }

    // epilogue: H2[m=quad*4+r][n2=nt*16+m16], bf16 store + stats
#pragma unroll
    for (int nt = 0; nt < NT2; ++nt) {
      float s = 0.f, ss = 0.f;
#pragma unroll
      for (int r = 0; r < 4; ++r) {
        int grow = row0 + quad * 4 + r;
        if (grow < M) {
          float v = acc2[nt][r];
          s += v;
          ss += v * v;
          O[(size_t)grow * N2 + nt * 16 + m16] = rne16(v);
        }
      }
      atomicAdd(&sSt[nt * 16 + m16], s);
      atomicAdd(&sSt[N2 + nt * 16 + m16], ss);
    }
  }
  __syncthreads();
  for (int i = tid; i < 2 * N2; i += 256) atomicAdd(&gstats[i], sSt[i]);
}

// ---------------------------------------------------------------- BN finalize: stats -> scale/shift
template <int DOUT>
__global__ void finalize_stats_kernel(float* __restrict__ stats, const float* __restrict__ g,
                                      const float* __restrict__ be) {
  int c = threadIdx.x;
  if (c < DOUT) {
    float inv_n = 1.0f / (float)N_NODES;
    float mean = stats[c] * inv_n;
    float var = stats[DOUT + c] * inv_n - mean * mean;
    float sc = g[c] * rsqrtf(var + BN_EPS);
    stats[2 * DOUT + c] = sc;
    stats[3 * DOUT + c] = be[c] - mean * sc;
  }
}

// ---------------------------------------------------------------- segmented mean pool (bf16 in, BN+ReLU fused)
__global__ __launch_bounds__(256) void pool_seg_kernel(
    const unsigned short* __restrict__ h, const float* __restrict__ scale,
    const float* __restrict__ shift, const int* __restrict__ batch,
    float* __restrict__ sums) {
  __shared__ float sacc[N_GRAPHS * 64];
  int tid = threadIdx.x;
  for (int i = tid; i < N_GRAPHS * 64; i += 256) sacc[i] = 0.f;

  int base = blockIdx.x * POOL_CHUNK;
  int last = min(base + POOL_CHUNK, N_NODES) - 1;
  int c4 = tid & 15;
  int r = tid >> 4;
  float4 sc = ((const float4*)scale)[c4];
  float4 sh = ((const float4*)shift)[c4];
  __syncthreads();

  float4 acc = make_float4(0.f, 0.f, 0.f, 0.f);
  int gcur = -1;
#pragma unroll 1
  for (int j = 0; j < POOL_CHUNK / 16; ++j) {
    int node = base + j * 16 + r;
    if (node >= N_NODES) break;
    int g = batch[node];
    if (g != gcur) {
      if (gcur >= 0) {
        float* p = &sacc[gcur * 64 + c4 * 4];
        atomicAdd(p + 0, acc.x); atomicAdd(p + 1, acc.y);
        atomicAdd(p + 2, acc.z); atomicAdd(p + 3, acc.w);
      }
      gcur = g;
      acc = make_float4(0.f, 0.f, 0.f, 0.f);
    }
    uint2 u = ((const uint2*)(h + (size_t)node * 64))[c4];
    float f0, f1, f2, f3;
    bf2_to_f32(u.x, f0, f1);
    bf2_to_f32(u.y, f2, f3);
    acc.x += fmaxf(fmaf(f0, sc.x, sh.x), 0.f);
    acc.y += fmaxf(fmaf(f1, sc.y, sh.y), 0.f);
    acc.z += fmaxf(fmaf(f2, sc.z, sh.z), 0.f);
    acc.w += fmaxf(fmaf(f3, sc.w, sh.w), 0.f);
  }
  if (gcur >= 0) {
    float* p = &sacc[gcur * 64 + c4 * 4];
    atomicAdd(p + 0, acc.x); atomicAdd(p + 1, acc.y);
    atomicAdd(p + 2, acc.z); atomicAdd(p + 3, acc.w);
  }
  __syncthreads();

  int gmin = batch[base];
  int gmax = batch[last];
  for (int g = gmin; g <= gmax; ++g)
    for (int i = tid; i < 64; i += 256)
      atomicAdd(&sums[g * 64 + i], sacc[g * 64 + i]);
}

// ---------------------------------------------------------------- divide by counts (binary search)
__global__ __launch_bounds__(256) void div_kernel(const float* __restrict__ sums,
                                                  const int* __restrict__ batch,
                                                  float* __restrict__ out) {
  int i = blockIdx.x * blockDim.x + threadIdx.x;
  if (i >= N_GRAPHS * 64) return;
  int g = i >> 6;
  int lo = 0, hi = N_NODES;
  while (lo < hi) { int m = (lo + hi) >> 1; if (batch[m] < g) lo = m + 1; else hi = m; }
  int lb = lo;
  lo = 0; hi = N_NODES;
  while (lo < hi) { int m = (lo + hi) >> 1; if (batch[m] <= g) lo = m + 1; else hi = m; }
  float cnt = (float)(lo - lb);
  out[i] = sums[i] / fmaxf(cnt, 1.0f);
}

// ---------------------------------------------------------------- launch
extern "C" void kernel_launch(void* const* d_in, const int* in_sizes, int n_in,
                              void* d_out, int out_size, void* d_ws, size_t ws_size,
                              hipStream_t stream) {
  const float* x = (const float*)d_in[0];
  const int* edge_index = (const int*)d_in[1];
  const int* batch = (const int*)d_in[2];
  const int* src = edge_index;
  const int* dst = edge_index + N_EDGES;

  const float* wa[3] = {(const float*)d_in[3], (const float*)d_in[9],  (const float*)d_in[15]};
  const float* ba[3] = {(const float*)d_in[4], (const float*)d_in[10], (const float*)d_in[16]};
  const float* wb[3] = {(const float*)d_in[5], (const float*)d_in[11], (const float*)d_in[17]};
  const float* bb[3] = {(const float*)d_in[6], (const float*)d_in[12], (const float*)d_in[18]};
  const float* gg[3] = {(const float*)d_in[7], (const float*)d_in[13], (const float*)d_in[19]};
  const float* be[3] = {(const float*)d_in[8], (const float*)d_in[14], (const float*)d_in[20]};

  // -------- workspace layout --------
  float* stats0 = (float*)d_ws;   // fp32 zeroed: stats0(512) stats1(512) stats2(256) psums(8192)
  float* stats1 = stats0 + 512;
  float* stats2 = stats1 + 512;
  float* psums = stats2 + 256;
  int* bcnt = (int*)(psums + (size_t)N_GRAPHS * 64);  // 256, zeroed with floats
  int* boff = bcnt + 256;
  int* bcur = boff + 256;
  int* row_ptr = bcur + 256;
  int* adj = row_ptr + 100004;
  unsigned* pairs = (unsigned*)(adj + N_EDGES);
  unsigned short* b0 = (unsigned short*)(pairs + N_EDGES);
  unsigned short* b1 = b0 + (size_t)N_NODES * 128;
  unsigned short* wf0 = b1 + (size_t)N_NODES * 128;
  unsigned short* wf[6];
  for (int i = 0; i < 6; ++i) wf[i] = wf0 + (size_t)i * 16384;
  size_t needed = (size_t)((char*)(wf0 + 6 * 16384) - (char*)d_ws);
  if (ws_size < needed) return;

  hipMemsetAsync(stats0, 0, 9472 * 4 + 256 * 4, stream);

  WPArgs wp;
  wp.w[0] = wa[0]; wp.w[1] = wb[0]; wp.w[2] = wa[1];
  wp.w[3] = wb[1]; wp.w[4] = wa[2]; wp.w[5] = wb[2];
  for (int i = 0; i < 6; ++i) wp.o[i] = wf[i];
  wprep_all_kernel<<<352, 256, 0, stream>>>(wp);

  bcount_kernel<<<PSC_BLOCKS, 256, 0, stream>>>(dst, bcnt);
  bscan_kernel<<<1, 256, 0, stream>>>(bcnt, boff, bcur, row_ptr);
  pscatter_kernel<<<PSC_BLOCKS, 256, 0, stream>>>(src, dst, bcur, pairs);
  bdeg_scan_kernel<<<NBUCKETS, 256, 0, stream>>>(pairs, boff, row_ptr);
  bfill_kernel<<<NBUCKETS, 256, 0, stream>>>(pairs, boff, row_ptr, adj);

  const int gather_blocks = (N_NODES * 16 + 255) / 256;
  const int fused_blocks = 768;  // 3 blocks/CU (50 KB LDS each), grid-stride over 1563 tiles

  // ---- layer 0: gather(x fp32) -> b0 ; fused MLP b0 -> b1
  gather_l0_kernel<<<gather_blocks, 256, 0, stream>>>(x, row_ptr, adj, b0);
  fused_mlp_kernel<128><<<fused_blocks, 256, 0, stream>>>(
      b0, wf[0], wf[1], ba[0], bb[0], b1, stats0, N_NODES, MLP_TILES);
  finalize_stats_kernel<128><<<1, 128, 0, stream>>>(stats0, gg[0], be[0]);

  // ---- layer 1: gather(b1, BN0) -> b0 ; fused MLP b0 -> b1
  gather_ln_kernel<<<gather_blocks, 256, 0, stream>>>(b1, stats0 + 256, stats0 + 384,
                                                      row_ptr, adj, b0);
  fused_mlp_kernel<128><<<fused_blocks, 256, 0, stream>>>(
      b0, wf[2], wf[3], ba[1], bb[1], b1, stats1, N_NODES, MLP_TILES);
  finalize_stats_kernel<128><<<1, 128, 0, stream>>>(stats1, gg[1], be[1]);

  // ---- layer 2: gather(b1, BN1) -> b0 ; fused MLP b0 -> b1 (N2=64)
  gather_ln_kernel<<<gather_blocks, 256, 0, stream>>>(b1, stats1 + 256, stats1 + 384,
                                                      row_ptr, adj, b0);
  fused_mlp_kernel<64><<<fused_blocks, 256, 0, stream>>>(
      b0, wf[4], wf[5], ba[2], bb[2], b1, stats2, N_NODES, MLP_TILES);
  finalize_stats_kernel<64><<<1, 64, 0, stream>>>(stats2, gg[2], be[2]);

  // ---- pool (BN2+ReLU fused) + divide
  pool_seg_kernel<<<POOL_BLOCKS, 256, 0, stream>>>(b1, stats2 + 128, stats2 + 192, batch, psums);
  div_kernel<<<32, 256, 0, stream>>>(psums, batch, (float*)d_out);
}